// Round 1
// baseline (2443.607 us; speedup 1.0000x reference)
//
#include <hip/hip_runtime.h>
#include <cstdint>
#include <cstddef>

#define HH 768
#define SS 512
#define NBATCH 8
#define NLH 12
#define HDIM 64
#define BSROWS 4096
static constexpr float NEGV = -1000000000000.0f;

// ---------------- tiled f32 GEMM: C[M,N] = A[M,K] @ W[K,N] + bias[N] (+ res[M,N])
// requires M%64==0, N%64==0, K%16==0
__global__ __launch_bounds__(256) void gemm_f32(
    const float* __restrict__ A, const float* __restrict__ W,
    const float* __restrict__ bias, const float* __restrict__ res,
    float* __restrict__ C, int M, int N, int K)
{
  __shared__ float As[16][68];
  __shared__ float Ws[16][68];
  const int tid = threadIdx.x;
  const int bm = blockIdx.y * 64;
  const int bn = blockIdx.x * 64;
  const int tr = tid >> 4;
  const int tc = tid & 15;
  const int ar = tid >> 2;
  const int ak = (tid & 3) << 2;
  const int wc = tid & 63;
  const int wk = tid >> 6;
  float acc[4][4] = {};
  for (int k0 = 0; k0 < K; k0 += 16) {
    float4 av = *(const float4*)(A + (size_t)(bm + ar) * K + (k0 + ak));
    As[ak + 0][ar] = av.x; As[ak + 1][ar] = av.y;
    As[ak + 2][ar] = av.z; As[ak + 3][ar] = av.w;
#pragma unroll
    for (int j = 0; j < 4; ++j)
      Ws[wk + j * 4][wc] = W[(size_t)(k0 + wk + j * 4) * N + (bn + wc)];
    __syncthreads();
#pragma unroll
    for (int kk = 0; kk < 16; ++kk) {
      float a[4], w[4];
#pragma unroll
      for (int i = 0; i < 4; ++i) a[i] = As[kk][tr * 4 + i];
#pragma unroll
      for (int j = 0; j < 4; ++j) w[j] = Ws[kk][tc * 4 + j];
#pragma unroll
      for (int i = 0; i < 4; ++i)
#pragma unroll
        for (int j = 0; j < 4; ++j)
          acc[i][j] = fmaf(a[i], w[j], acc[i][j]);
    }
    __syncthreads();
  }
#pragma unroll
  for (int i = 0; i < 4; ++i) {
    const int row = bm + tr * 4 + i;
#pragma unroll
    for (int j = 0; j < 4; ++j) {
      const int col = bn + tc * 4 + j;
      float v = acc[i][j] + bias[col];
      if (res) v += res[(size_t)row * N + col];
      C[(size_t)row * N + col] = v;
    }
  }
}

// ---------------- small-M GEMM (M<=8): one thread per (m,n)
__global__ void gemm_small(
    const float* __restrict__ A, const float* __restrict__ W,
    const float* __restrict__ bias, const float* __restrict__ res,
    float* __restrict__ C, int M, int N, int K)
{
  int n = blockIdx.x * blockDim.x + threadIdx.x;
  int m = blockIdx.y;
  if (n >= N || m >= M) return;
  float acc = 0.f;
  for (int k = 0; k < K; ++k) acc = fmaf(A[(size_t)m * K + k], W[(size_t)k * N + n], acc);
  float v = acc + bias[n];
  if (res) v += res[(size_t)m * N + n];
  C[(size_t)m * N + n] = v;
}

// ---------------- center = mean over s of hidden0
__global__ void mean_kernel(const float* __restrict__ h0, float* __restrict__ center)
{
  int idx = blockIdx.x * blockDim.x + threadIdx.x; // b*768+h
  if (idx >= NBATCH * HH) return;
  int b = idx / HH, h = idx % HH;
  const float* p = h0 + (size_t)b * SS * HH + h;
  float s = 0.f;
  for (int i = 0; i < SS; ++i) s += p[(size_t)i * HH];
  center[idx] = s * (1.0f / SS);
}

// ---------------- star attention: 5 keys per query, per (row, head)
__global__ __launch_bounds__(256) void sat_attn(
    const float* __restrict__ Qc, const float* __restrict__ Kc, const float* __restrict__ Vc,
    const float* __restrict__ Kh0, const float* __restrict__ Vh0,
    const float* __restrict__ Kcen, const float* __restrict__ Vcen,
    float* __restrict__ ctx)
{
  int i = blockIdx.x;             // 0..4095 (b*512+s)
  int b = i >> 9, s = i & 511;
  int lane = threadIdx.x & 63;
  int wave = threadIdx.x >> 6;    // 0..3
  size_t rb = (size_t)(b * SS + ((s + 1) & 511)) * HH;
  size_t rs = (size_t)i * HH;
  size_t ra = (size_t)(b * SS + (s == 0 ? (SS - 1) : 0)) * HH;
  size_t rc = (size_t)b * HH;
  for (int h = wave; h < NLH; h += 4) {
    int off = h * HDIM + lane;
    float q = Qc[rs + off];
    float s0 = q * Kc[rb + off];
    float s1 = q * Kc[rs + off];
    float s2 = q * Kc[ra + off];
    float s3 = q * Kh0[rs + off];
    float s4 = q * Kcen[rc + off];
#pragma unroll
    for (int d = 1; d < 64; d <<= 1) {
      s0 += __shfl_xor(s0, d); s1 += __shfl_xor(s1, d); s2 += __shfl_xor(s2, d);
      s3 += __shfl_xor(s3, d); s4 += __shfl_xor(s4, d);
    }
    const float sc = 0.125f;
    s0 *= sc; s1 *= sc; s2 *= sc; s3 *= sc; s4 *= sc;
    float mx = fmaxf(fmaxf(fmaxf(s0, s1), fmaxf(s2, s3)), s4);
    float e0 = __expf(s0 - mx), e1 = __expf(s1 - mx), e2 = __expf(s2 - mx);
    float e3 = __expf(s3 - mx), e4 = __expf(s4 - mx);
    float inv = 1.f / (e0 + e1 + e2 + e3 + e4);
    float v = e0 * Vc[rb + off] + e1 * Vc[rs + off] + e2 * Vc[ra + off]
            + e3 * Vh0[rs + off] + e4 * Vcen[rc + off];
    ctx[rs + off] = v * inv;
  }
}

// ---------------- relu + layernorm over rows of 768
__global__ __launch_bounds__(256) void relu_ln(
    const float* __restrict__ x, const float* __restrict__ w, const float* __restrict__ b,
    float* __restrict__ y)
{
  int row = blockIdx.x;
  const float* xr = x + (size_t)row * HH;
  float v[3];
  float sum = 0.f, sumsq = 0.f;
#pragma unroll
  for (int j = 0; j < 3; ++j) {
    float t = xr[threadIdx.x + j * 256];
    t = fmaxf(t, 0.f);
    v[j] = t;
    sum += t; sumsq += t * t;
  }
#pragma unroll
  for (int d = 1; d < 64; d <<= 1) { sum += __shfl_xor(sum, d); sumsq += __shfl_xor(sumsq, d); }
  __shared__ float ws_[4], wsq_[4];
  int wave = threadIdx.x >> 6, lane = threadIdx.x & 63;
  if (lane == 0) { ws_[wave] = sum; wsq_[wave] = sumsq; }
  __syncthreads();
  sum = ws_[0] + ws_[1] + ws_[2] + ws_[3];
  sumsq = wsq_[0] + wsq_[1] + wsq_[2] + wsq_[3];
  float mean = sum * (1.0f / HH);
  float var = sumsq * (1.0f / HH) - mean * mean;
  float rstd = rsqrtf(var + 1e-12f);
#pragma unroll
  for (int j = 0; j < 3; ++j) {
    int c = threadIdx.x + j * 256;
    y[(size_t)row * HH + c] = w[c] * (v[j] - mean) * rstd + b[c];
  }
}

// ---------------- rel attention: 8 batches x 12 heads, 513 keys
__global__ __launch_bounds__(256) void rel_attn(
    const float* __restrict__ Qr, const float* __restrict__ Krc, const float* __restrict__ Kr,
    const float* __restrict__ Vrc, const float* __restrict__ Vr, float* __restrict__ ctx)
{
  int b = blockIdx.x, h = blockIdx.y;
  __shared__ float qs[64];
  __shared__ float sc[513];
  __shared__ float part[4][64];
  __shared__ float redm[4], redsum[4];
  int t = threadIdx.x, lane = t & 63, wave = t >> 6;
  if (t < 64) qs[t] = Qr[b * HH + h * HDIM + t];
  __syncthreads();
  for (int j = t; j < 513; j += 256) {
    const float* kp = (j == 0) ? (Krc + b * HH + h * HDIM)
                               : (Kr + (size_t)(b * SS + j - 1) * HH + h * HDIM);
    float acc = 0.f;
    for (int d = 0; d < HDIM; ++d) acc = fmaf(qs[d], kp[d], acc);
    sc[j] = acc * 0.125f;
  }
  __syncthreads();
  float m = -1e30f;
  for (int j = t; j < 513; j += 256) m = fmaxf(m, sc[j]);
#pragma unroll
  for (int d = 1; d < 64; d <<= 1) m = fmaxf(m, __shfl_xor(m, d));
  if (lane == 0) redm[wave] = m;
  __syncthreads();
  m = fmaxf(fmaxf(redm[0], redm[1]), fmaxf(redm[2], redm[3]));
  float lsum = 0.f;
  for (int j = t; j < 513; j += 256) { float e = __expf(sc[j] - m); sc[j] = e; lsum += e; }
#pragma unroll
  for (int d = 1; d < 64; d <<= 1) lsum += __shfl_xor(lsum, d);
  if (lane == 0) redsum[wave] = lsum;
  __syncthreads();
  float total = redsum[0] + redsum[1] + redsum[2] + redsum[3];
  float accv = 0.f;
  for (int j = wave; j < 513; j += 4) {
    const float* vp = (j == 0) ? (Vrc + b * HH + h * HDIM)
                               : (Vr + (size_t)(b * SS + j - 1) * HH + h * HDIM);
    accv = fmaf(sc[j], vp[lane], accv);
  }
  part[wave][lane] = accv;
  __syncthreads();
  if (wave == 0) {
    float r = (part[0][lane] + part[1][lane] + part[2][lane] + part[3][lane]) / total;
    ctx[b * HH + h * HDIM + lane] = r;
  }
}

// ---------------- tail: bias2[row,c] = (outputs[row,:] @ tail_w + tail_b)[c] * 0.5
__global__ void tail_gemm(const float* __restrict__ A, const float* __restrict__ W,
                          const float* __restrict__ bias, float* __restrict__ C)
{
  int idx = blockIdx.x * blockDim.x + threadIdx.x;
  if (idx >= BSROWS * 24) return;
  int row = idx / 24, c = idx % 24;
  float acc = bias[c];
  const float* a = A + (size_t)row * 128;
  for (int k = 0; k < 128; ++k) acc = fmaf(a[k], W[k * 24 + c], acc);
  C[idx] = acc * 0.5f;
}

// ---------------- RoPE split: outputs (4096,128) -> qw_rot, kw_rot (4096,64)
__global__ void rope_kernel(const float* __restrict__ outputs,
                            float* __restrict__ qw, float* __restrict__ kw)
{
  int idx = blockIdx.x * blockDim.x + threadIdx.x; // row*32 + i
  if (idx >= BSROWS * 32) return;
  int row = idx >> 5;
  int i = idx & 31;
  int s = row & 511;
  float inv = powf(10000.0f, -2.0f * (float)i / 64.0f);
  float ang = (float)s * inv;
  float sn = sinf(ang), cn = cosf(ang);
  const float* o = outputs + (size_t)row * 128 + i * 4;
  float q0 = o[0], k0 = o[1], q1 = o[2], k1 = o[3];
  float* qp = qw + (size_t)row * 64 + i * 2;
  float* kp = kw + (size_t)row * 64 + i * 2;
  qp[0] = q0 * cn - q1 * sn; qp[1] = q1 * cn + q0 * sn;
  kp[0] = k0 * cn - k1 * sn; kp[1] = k1 * cn + k0 * sn;
}

// ---------------- final: out[b,h,m,n] = qk/8 + bias2[b,n,2h] + bias2[b,m,2h+1], masks, tril
__global__ __launch_bounds__(256) void final_kernel(
    const float* __restrict__ qw, const float* __restrict__ kw,
    const float* __restrict__ bias2, const float* __restrict__ mask,
    float* __restrict__ out)
{
  int b = blockIdx.z;
  int mt = blockIdx.y * 32;
  int nt = blockIdx.x * 32;
  __shared__ float qs[32][68];
  __shared__ float ks[32][68];
  int t = threadIdx.x;
  {
    int idx = t * 8;
    int r = idx >> 6, c = idx & 63;
    const float* sq = qw + (size_t)(b * SS + mt + r) * 64 + c;
    const float* sk = kw + (size_t)(b * SS + nt + r) * 64 + c;
    *(float4*)&qs[r][c]     = *(const float4*)(sq);
    *(float4*)&qs[r][c + 4] = *(const float4*)(sq + 4);
    *(float4*)&ks[r][c]     = *(const float4*)(sk);
    *(float4*)&ks[r][c + 4] = *(const float4*)(sk + 4);
  }
  __syncthreads();
  int m = t >> 3;
  int n0 = (t & 7) * 4;
  float d0 = 0.f, d1 = 0.f, d2 = 0.f, d3 = 0.f;
#pragma unroll
  for (int d = 0; d < 64; d += 4) {
    float4 qv = *(const float4*)&qs[m][d];
    float4 k0 = *(const float4*)&ks[n0 + 0][d];
    float4 k1 = *(const float4*)&ks[n0 + 1][d];
    float4 k2 = *(const float4*)&ks[n0 + 2][d];
    float4 k3 = *(const float4*)&ks[n0 + 3][d];
    d0 += qv.x * k0.x + qv.y * k0.y + qv.z * k0.z + qv.w * k0.w;
    d1 += qv.x * k1.x + qv.y * k1.y + qv.z * k1.z + qv.w * k1.w;
    d2 += qv.x * k2.x + qv.y * k2.y + qv.z * k2.z + qv.w * k2.w;
    d3 += qv.x * k3.x + qv.y * k3.y + qv.z * k3.z + qv.w * k3.w;
  }
  int gm = mt + m;
  int gn = nt + n0;
  d0 *= 0.125f; d1 *= 0.125f; d2 *= 0.125f; d3 *= 0.125f;
  float mm = mask[b * SS + gm];
  float mn0 = mask[b * SS + gn + 0];
  float mn1 = mask[b * SS + gn + 1];
  float mn2 = mask[b * SS + gn + 2];
  float mn3 = mask[b * SS + gn + 3];
  const float* bmp = bias2 + (size_t)(b * SS + gm) * 24;
  const float* bnp0 = bias2 + (size_t)(b * SS + gn + 0) * 24;
  const float* bnp1 = bias2 + (size_t)(b * SS + gn + 1) * 24;
  const float* bnp2 = bias2 + (size_t)(b * SS + gn + 2) * 24;
  const float* bnp3 = bias2 + (size_t)(b * SS + gn + 3) * 24;
#pragma unroll
  for (int h = 0; h < NLH; ++h) {
    float tb = bmp[2 * h + 1];
    float v0 = d0 + bnp0[2 * h] + tb;
    float v1 = d1 + bnp1[2 * h] + tb;
    float v2 = d2 + bnp2[2 * h] + tb;
    float v3 = d3 + bnp3[2 * h] + tb;
    v0 = v0 * mm + NEGV * (1.f - mm); v1 = v1 * mm + NEGV * (1.f - mm);
    v2 = v2 * mm + NEGV * (1.f - mm); v3 = v3 * mm + NEGV * (1.f - mm);
    v0 = v0 * mn0 + NEGV * (1.f - mn0); v1 = v1 * mn1 + NEGV * (1.f - mn1);
    v2 = v2 * mn2 + NEGV * (1.f - mn2); v3 = v3 * mn3 + NEGV * (1.f - mn3);
    if (gm > gn + 0) v0 -= 1000000000000.0f;
    if (gm > gn + 1) v1 -= 1000000000000.0f;
    if (gm > gn + 2) v2 -= 1000000000000.0f;
    if (gm > gn + 3) v3 -= 1000000000000.0f;
    float4 o = make_float4(v0, v1, v2, v3);
    *(float4*)(out + ((((size_t)(b * NLH + h)) * SS + gm) * SS + gn)) = o;
  }
}

extern "C" void kernel_launch(void* const* d_in, const int* in_sizes, int n_in,
                              void* d_out, int out_size, void* d_ws, size_t ws_size,
                              hipStream_t stream)
{
  const float* bert    = (const float*)d_in[0];
  const float* amask   = (const float*)d_in[1];
  const float* dense_w = (const float*)d_in[2];
  const float* dense_b = (const float*)d_in[3];
  const float* sat_qw  = (const float*)d_in[4];
  const float* sat_qb  = (const float*)d_in[5];
  const float* sat_kw  = (const float*)d_in[6];
  const float* sat_kb  = (const float*)d_in[7];
  const float* sat_vw  = (const float*)d_in[8];
  const float* sat_vb  = (const float*)d_in[9];
  const float* sat_ow  = (const float*)d_in[10];
  const float* sat_ob  = (const float*)d_in[11];
  const float* rel_qw  = (const float*)d_in[12];
  const float* rel_qb  = (const float*)d_in[13];
  const float* rel_kw  = (const float*)d_in[14];
  const float* rel_kb  = (const float*)d_in[15];
  const float* rel_vw  = (const float*)d_in[16];
  const float* rel_vb  = (const float*)d_in[17];
  const float* rel_ow  = (const float*)d_in[18];
  const float* rel_ob  = (const float*)d_in[19];
  const float* lns_w   = (const float*)d_in[20];
  const float* lns_b   = (const float*)d_in[21];
  const float* lnr_w   = (const float*)d_in[22];
  const float* lnr_b   = (const float*)d_in[23];
  const float* head_w  = (const float*)d_in[24];
  const float* head_b  = (const float*)d_in[25];
  const float* tail_w  = (const float*)d_in[26];
  const float* tail_b  = (const float*)d_in[27];

  float* out = (float*)d_out;
  float* ws  = (float*)d_ws;

  const size_t NH = (size_t)BSROWS * HH; // 3145728
  float* hidden0 = ws;
  float* csA     = ws + NH;
  float* ctx     = ws + 2 * NH;
  float* sm      = ws + 3 * NH;
  float* center  = sm + 0 * 6144;
  float* center2 = sm + 1 * 6144;
  float* Kcen    = sm + 2 * 6144;
  float* Vcen    = sm + 3 * 6144;
  float* Qr      = sm + 4 * 6144;
  float* Krc     = sm + 5 * 6144;
  float* Vrc     = sm + 6 * 6144;
  float* ctxr    = sm + 7 * 6144;
  float* relo    = sm + 8 * 6144;
  float* outputs = sm + 9 * 6144;
  float* bias2   = outputs + (size_t)BSROWS * 128;
  float* qwbuf   = bias2 + (size_t)BSROWS * 24;
  float* kwbuf   = qwbuf + (size_t)BSROWS * 64;

  // d_out used as scratch until the final kernel overwrites it completely
  float* Kh0  = out;
  float* Vh0  = out + NH;
  float* Qbuf = out + 2 * NH;
  float* Kbuf = out + 3 * NH;

  dim3 blk(256);
  dim3 g768(12, 64);

  // hidden0 = bert @ dense_w + dense_b
  gemm_f32<<<g768, blk, 0, stream>>>(bert, dense_w, dense_b, nullptr, hidden0, BSROWS, HH, 432);
  // center = mean_s hidden0
  mean_kernel<<<24, 256, 0, stream>>>(hidden0, center);
  // sat K/V of hidden0 (also serves as iter-1 K/V of cs)
  gemm_f32<<<g768, blk, 0, stream>>>(hidden0, sat_kw, sat_kb, nullptr, Kh0, BSROWS, HH, HH);
  gemm_f32<<<g768, blk, 0, stream>>>(hidden0, sat_vw, sat_vb, nullptr, Vh0, BSROWS, HH, HH);

  // ---- iter 1 (cs = hidden0) ----
  gemm_f32<<<g768, blk, 0, stream>>>(hidden0, sat_qw, sat_qb, nullptr, Qbuf, BSROWS, HH, HH);
  gemm_small<<<dim3(3, 8), blk, 0, stream>>>(center, sat_kw, sat_kb, nullptr, Kcen, 8, HH, HH);
  gemm_small<<<dim3(3, 8), blk, 0, stream>>>(center, sat_vw, sat_vb, nullptr, Vcen, 8, HH, HH);
  sat_attn<<<BSROWS, 256, 0, stream>>>(Qbuf, Kh0, Vh0, Kh0, Vh0, Kcen, Vcen, ctx);
  gemm_f32<<<g768, blk, 0, stream>>>(ctx, sat_ow, sat_ob, hidden0, Kbuf, BSROWS, HH, HH);
  relu_ln<<<BSROWS, 256, 0, stream>>>(Kbuf, lns_w, lns_b, csA);
  // rel branch (only needed in iter 1; iter-2 center is dead)
  gemm_small<<<dim3(3, 8), blk, 0, stream>>>(center, rel_qw, rel_qb, nullptr, Qr, 8, HH, HH);
  gemm_small<<<dim3(3, 8), blk, 0, stream>>>(center, rel_kw, rel_kb, nullptr, Krc, 8, HH, HH);
  gemm_small<<<dim3(3, 8), blk, 0, stream>>>(center, rel_vw, rel_vb, nullptr, Vrc, 8, HH, HH);
  gemm_f32<<<g768, blk, 0, stream>>>(csA, rel_kw, rel_kb, nullptr, Qbuf, BSROWS, HH, HH); // Kr
  gemm_f32<<<g768, blk, 0, stream>>>(csA, rel_vw, rel_vb, nullptr, ctx, BSROWS, HH, HH);  // Vr
  rel_attn<<<dim3(8, 12), 256, 0, stream>>>(Qr, Krc, Qbuf, Vrc, ctx, ctxr);
  gemm_small<<<dim3(3, 8), blk, 0, stream>>>(ctxr, rel_ow, rel_ob, center, relo, 8, HH, HH);
  relu_ln<<<8, 256, 0, stream>>>(relo, lnr_w, lnr_b, center2);

  // ---- iter 2 (cs = csA, center = center2) ----
  gemm_f32<<<g768, blk, 0, stream>>>(csA, sat_qw, sat_qb, nullptr, Qbuf, BSROWS, HH, HH);
  gemm_f32<<<g768, blk, 0, stream>>>(csA, sat_kw, sat_kb, nullptr, Kbuf, BSROWS, HH, HH);
  gemm_f32<<<g768, blk, 0, stream>>>(csA, sat_vw, sat_vb, nullptr, hidden0, BSROWS, HH, HH); // Vc2
  gemm_small<<<dim3(3, 8), blk, 0, stream>>>(center2, sat_kw, sat_kb, nullptr, Kcen, 8, HH, HH);
  gemm_small<<<dim3(3, 8), blk, 0, stream>>>(center2, sat_vw, sat_vb, nullptr, Vcen, 8, HH, HH);
  sat_attn<<<BSROWS, 256, 0, stream>>>(Qbuf, Kbuf, hidden0, Kh0, Vh0, Kcen, Vcen, ctx);
  gemm_f32<<<g768, blk, 0, stream>>>(ctx, sat_ow, sat_ob, csA, Qbuf, BSROWS, HH, HH);
  relu_ln<<<BSROWS, 256, 0, stream>>>(Qbuf, lns_w, lns_b, csA);

  // ---- head / rope / logits ----
  gemm_f32<<<dim3(2, 64), blk, 0, stream>>>(csA, head_w, head_b, nullptr, outputs, BSROWS, 128, HH);
  tail_gemm<<<384, 256, 0, stream>>>(outputs, tail_w, tail_b, bias2);
  rope_kernel<<<512, 256, 0, stream>>>(outputs, qwbuf, kwbuf);
  final_kernel<<<dim3(16, 16, 8), 256, 0, stream>>>(qwbuf, kwbuf, bias2, amask, out);
}

// Round 2
// 1035.561 us; speedup vs baseline: 2.3597x; 2.3597x over previous
//
#include <hip/hip_runtime.h>
#include <cstdint>
#include <cstddef>

#define HH 768
#define SS 512
#define NBATCH 8
#define NLH 12
#define HDIM 64
#define BSROWS 4096
static constexpr float NEGV = -1000000000000.0f;

// ---------------- tiled f32 GEMM: C[M,N] = A[M,K] @ W[K,N] + bias[N] (+ res[M,N])
// requires M%64==0, N%64==0, K%16==0
__global__ __launch_bounds__(256) void gemm_f32(
    const float* __restrict__ A, const float* __restrict__ W,
    const float* __restrict__ bias, const float* __restrict__ res,
    float* __restrict__ C, int M, int N, int K)
{
  __shared__ float As[16][68];
  __shared__ float Ws[16][68];
  const int tid = threadIdx.x;
  const int bm = blockIdx.y * 64;
  const int bn = blockIdx.x * 64;
  const int tr = tid >> 4;
  const int tc = tid & 15;
  const int ar = tid >> 2;
  const int ak = (tid & 3) << 2;
  const int wc = tid & 63;
  const int wk = tid >> 6;
  float acc[4][4] = {};
  for (int k0 = 0; k0 < K; k0 += 16) {
    float4 av = *(const float4*)(A + (size_t)(bm + ar) * K + (k0 + ak));
    As[ak + 0][ar] = av.x; As[ak + 1][ar] = av.y;
    As[ak + 2][ar] = av.z; As[ak + 3][ar] = av.w;
#pragma unroll
    for (int j = 0; j < 4; ++j)
      Ws[wk + j * 4][wc] = W[(size_t)(k0 + wk + j * 4) * N + (bn + wc)];
    __syncthreads();
#pragma unroll
    for (int kk = 0; kk < 16; ++kk) {
      float a[4], w[4];
#pragma unroll
      for (int i = 0; i < 4; ++i) a[i] = As[kk][tr * 4 + i];
#pragma unroll
      for (int j = 0; j < 4; ++j) w[j] = Ws[kk][tc * 4 + j];
#pragma unroll
      for (int i = 0; i < 4; ++i)
#pragma unroll
        for (int j = 0; j < 4; ++j)
          acc[i][j] = fmaf(a[i], w[j], acc[i][j]);
    }
    __syncthreads();
  }
#pragma unroll
  for (int i = 0; i < 4; ++i) {
    const int row = bm + tr * 4 + i;
#pragma unroll
    for (int j = 0; j < 4; ++j) {
      const int col = bn + tc * 4 + j;
      float v = acc[i][j] + bias[col];
      if (res) v += res[(size_t)row * N + col];
      C[(size_t)row * N + col] = v;
    }
  }
}

// ---------------- skinny GEMM: M=8, K=768, N=768, multiple weight jobs per launch
struct SmallJob { const float* W; const float* bias; const float* res; float* C; };
struct SmallJobs { SmallJob j[5]; };

__global__ __launch_bounds__(256) void gemm_skinny(
    const float* __restrict__ A, SmallJobs jobs)
{
  __shared__ float As[8 * HH];            // 24 KB
  __shared__ float part[8 * 8 * 32];      // [ks][m][c] 8 KB
  const int tid = threadIdx.x;
  const SmallJob job = jobs.j[blockIdx.y];

  // stage A (8x768 contiguous)
#pragma unroll
  for (int i = 0; i < 6; ++i) {
    int idx = tid * 4 + i * 1024;
    *(float4*)&As[idx] = *(const float4*)(A + idx);
  }
  __syncthreads();

  const int c = tid & 31;
  const int col = (blockIdx.x << 5) + c;
  const int ks = tid >> 5;                // 0..7, 96 k each
  const float* Wp = job.W + (size_t)(ks * 96) * HH + col;
  float acc[8] = {};
#pragma unroll 8
  for (int k = 0; k < 96; ++k) {
    float w = Wp[(size_t)k * HH];
    const float* ap = &As[ks * 96 + k];
#pragma unroll
    for (int m = 0; m < 8; ++m)
      acc[m] = fmaf(ap[m * HH], w, acc[m]);
  }
#pragma unroll
  for (int m = 0; m < 8; ++m)
    part[ks * 256 + m * 32 + c] = acc[m];
  __syncthreads();

  // tid -> (m = tid>>5, c2 = tid&31)
  const int m = tid >> 5;
  const int c2 = tid & 31;
  float s = 0.f;
#pragma unroll
  for (int k = 0; k < 8; ++k) s += part[k * 256 + m * 32 + c2];
  const int outcol = (blockIdx.x << 5) + c2;
  float v = s + job.bias[outcol];
  if (job.res) v += job.res[(size_t)m * HH + outcol];
  job.C[(size_t)m * HH + outcol] = v;
}

// ---------------- center = mean over s of hidden0
__global__ void mean_kernel(const float* __restrict__ h0, float* __restrict__ center)
{
  int idx = blockIdx.x * blockDim.x + threadIdx.x; // b*768+h
  if (idx >= NBATCH * HH) return;
  int b = idx / HH, h = idx % HH;
  const float* p = h0 + (size_t)b * SS * HH + h;
  float s = 0.f;
  for (int i = 0; i < SS; ++i) s += p[(size_t)i * HH];
  center[idx] = s * (1.0f / SS);
}

// ---------------- star attention: 5 keys per query, per (row, head)
__global__ __launch_bounds__(256) void sat_attn(
    const float* __restrict__ Qc, const float* __restrict__ Kc, const float* __restrict__ Vc,
    const float* __restrict__ Kh0, const float* __restrict__ Vh0,
    const float* __restrict__ Kcen, const float* __restrict__ Vcen,
    float* __restrict__ ctx)
{
  int i = blockIdx.x;             // 0..4095 (b*512+s)
  int b = i >> 9, s = i & 511;
  int lane = threadIdx.x & 63;
  int wave = threadIdx.x >> 6;    // 0..3
  size_t rb = (size_t)(b * SS + ((s + 1) & 511)) * HH;
  size_t rs = (size_t)i * HH;
  size_t ra = (size_t)(b * SS + (s == 0 ? (SS - 1) : 0)) * HH;
  size_t rc = (size_t)b * HH;
  for (int h = wave; h < NLH; h += 4) {
    int off = h * HDIM + lane;
    float q = Qc[rs + off];
    float s0 = q * Kc[rb + off];
    float s1 = q * Kc[rs + off];
    float s2 = q * Kc[ra + off];
    float s3 = q * Kh0[rs + off];
    float s4 = q * Kcen[rc + off];
#pragma unroll
    for (int d = 1; d < 64; d <<= 1) {
      s0 += __shfl_xor(s0, d); s1 += __shfl_xor(s1, d); s2 += __shfl_xor(s2, d);
      s3 += __shfl_xor(s3, d); s4 += __shfl_xor(s4, d);
    }
    const float sc = 0.125f;
    s0 *= sc; s1 *= sc; s2 *= sc; s3 *= sc; s4 *= sc;
    float mx = fmaxf(fmaxf(fmaxf(s0, s1), fmaxf(s2, s3)), s4);
    float e0 = __expf(s0 - mx), e1 = __expf(s1 - mx), e2 = __expf(s2 - mx);
    float e3 = __expf(s3 - mx), e4 = __expf(s4 - mx);
    float inv = 1.f / (e0 + e1 + e2 + e3 + e4);
    float v = e0 * Vc[rb + off] + e1 * Vc[rs + off] + e2 * Vc[ra + off]
            + e3 * Vh0[rs + off] + e4 * Vcen[rc + off];
    ctx[rs + off] = v * inv;
  }
}

// ---------------- relu + layernorm over rows of 768
__global__ __launch_bounds__(256) void relu_ln(
    const float* __restrict__ x, const float* __restrict__ w, const float* __restrict__ b,
    float* __restrict__ y)
{
  int row = blockIdx.x;
  const float* xr = x + (size_t)row * HH;
  float v[3];
  float sum = 0.f, sumsq = 0.f;
#pragma unroll
  for (int j = 0; j < 3; ++j) {
    float t = xr[threadIdx.x + j * 256];
    t = fmaxf(t, 0.f);
    v[j] = t;
    sum += t; sumsq += t * t;
  }
#pragma unroll
  for (int d = 1; d < 64; d <<= 1) { sum += __shfl_xor(sum, d); sumsq += __shfl_xor(sumsq, d); }
  __shared__ float ws_[4], wsq_[4];
  int wave = threadIdx.x >> 6, lane = threadIdx.x & 63;
  if (lane == 0) { ws_[wave] = sum; wsq_[wave] = sumsq; }
  __syncthreads();
  sum = ws_[0] + ws_[1] + ws_[2] + ws_[3];
  sumsq = wsq_[0] + wsq_[1] + wsq_[2] + wsq_[3];
  float mean = sum * (1.0f / HH);
  float var = sumsq * (1.0f / HH) - mean * mean;
  float rstd = rsqrtf(var + 1e-12f);
#pragma unroll
  for (int j = 0; j < 3; ++j) {
    int c = threadIdx.x + j * 256;
    y[(size_t)row * HH + c] = w[c] * (v[j] - mean) * rstd + b[c];
  }
}

// ---------------- rel attention: 8 batches x 12 heads, 513 keys
__global__ __launch_bounds__(256) void rel_attn(
    const float* __restrict__ Qr, const float* __restrict__ Krc, const float* __restrict__ Kr,
    const float* __restrict__ Vrc, const float* __restrict__ Vr, float* __restrict__ ctx)
{
  int b = blockIdx.x, h = blockIdx.y;
  __shared__ float qs[64];
  __shared__ float sc[513];
  __shared__ float part[4][64];
  __shared__ float redm[4], redsum[4];
  int t = threadIdx.x, lane = t & 63, wave = t >> 6;
  if (t < 64) qs[t] = Qr[b * HH + h * HDIM + t];
  __syncthreads();
  for (int j = t; j < 513; j += 256) {
    const float* kp = (j == 0) ? (Krc + b * HH + h * HDIM)
                               : (Kr + (size_t)(b * SS + j - 1) * HH + h * HDIM);
    float acc = 0.f;
    for (int d = 0; d < HDIM; ++d) acc = fmaf(qs[d], kp[d], acc);
    sc[j] = acc * 0.125f;
  }
  __syncthreads();
  float m = -1e30f;
  for (int j = t; j < 513; j += 256) m = fmaxf(m, sc[j]);
#pragma unroll
  for (int d = 1; d < 64; d <<= 1) m = fmaxf(m, __shfl_xor(m, d));
  if (lane == 0) redm[wave] = m;
  __syncthreads();
  m = fmaxf(fmaxf(redm[0], redm[1]), fmaxf(redm[2], redm[3]));
  float lsum = 0.f;
  for (int j = t; j < 513; j += 256) { float e = __expf(sc[j] - m); sc[j] = e; lsum += e; }
#pragma unroll
  for (int d = 1; d < 64; d <<= 1) lsum += __shfl_xor(lsum, d);
  if (lane == 0) redsum[wave] = lsum;
  __syncthreads();
  float total = redsum[0] + redsum[1] + redsum[2] + redsum[3];
  float accv = 0.f;
  for (int j = wave; j < 513; j += 4) {
    const float* vp = (j == 0) ? (Vrc + b * HH + h * HDIM)
                               : (Vr + (size_t)(b * SS + j - 1) * HH + h * HDIM);
    accv = fmaf(sc[j], vp[lane], accv);
  }
  part[wave][lane] = accv;
  __syncthreads();
  if (wave == 0) {
    float r = (part[0][lane] + part[1][lane] + part[2][lane] + part[3][lane]) / total;
    ctx[b * HH + h * HDIM + lane] = r;
  }
}

// ---------------- tail: bias2[row,c] = (outputs[row,:] @ tail_w + tail_b)[c] * 0.5
__global__ void tail_gemm(const float* __restrict__ A, const float* __restrict__ W,
                          const float* __restrict__ bias, float* __restrict__ C)
{
  int idx = blockIdx.x * blockDim.x + threadIdx.x;
  if (idx >= BSROWS * 24) return;
  int row = idx / 24, c = idx % 24;
  float acc = bias[c];
  const float* a = A + (size_t)row * 128;
  for (int k = 0; k < 128; ++k) acc = fmaf(a[k], W[k * 24 + c], acc);
  C[idx] = acc * 0.5f;
}

// ---------------- RoPE split: outputs (4096,128) -> qw_rot, kw_rot (4096,64)
__global__ void rope_kernel(const float* __restrict__ outputs,
                            float* __restrict__ qw, float* __restrict__ kw)
{
  int idx = blockIdx.x * blockDim.x + threadIdx.x; // row*32 + i
  if (idx >= BSROWS * 32) return;
  int row = idx >> 5;
  int i = idx & 31;
  int s = row & 511;
  float inv = powf(10000.0f, -2.0f * (float)i / 64.0f);
  float ang = (float)s * inv;
  float sn = sinf(ang), cn = cosf(ang);
  const float* o = outputs + (size_t)row * 128 + i * 4;
  float q0 = o[0], k0 = o[1], q1 = o[2], k1 = o[3];
  float* qp = qw + (size_t)row * 64 + i * 2;
  float* kp = kw + (size_t)row * 64 + i * 2;
  qp[0] = q0 * cn - q1 * sn; qp[1] = q1 * cn + q0 * sn;
  kp[0] = k0 * cn - k1 * sn; kp[1] = k1 * cn + k0 * sn;
}

// ---------------- final: out[b,h,m,n] = qk/8 + bias2[b,n,2h] + bias2[b,m,2h+1], masks, tril
__global__ __launch_bounds__(256) void final_kernel(
    const float* __restrict__ qw, const float* __restrict__ kw,
    const float* __restrict__ bias2, const float* __restrict__ mask,
    float* __restrict__ out)
{
  int b = blockIdx.z;
  int mt = blockIdx.y * 32;
  int nt = blockIdx.x * 32;
  __shared__ float qs[32][68];
  __shared__ float ks[32][68];
  int t = threadIdx.x;
  {
    int idx = t * 8;
    int r = idx >> 6, c = idx & 63;
    const float* sq = qw + (size_t)(b * SS + mt + r) * 64 + c;
    const float* sk = kw + (size_t)(b * SS + nt + r) * 64 + c;
    *(float4*)&qs[r][c]     = *(const float4*)(sq);
    *(float4*)&qs[r][c + 4] = *(const float4*)(sq + 4);
    *(float4*)&ks[r][c]     = *(const float4*)(sk);
    *(float4*)&ks[r][c + 4] = *(const float4*)(sk + 4);
  }
  __syncthreads();
  int m = t >> 3;
  int n0 = (t & 7) * 4;
  float d0 = 0.f, d1 = 0.f, d2 = 0.f, d3 = 0.f;
#pragma unroll
  for (int d = 0; d < 64; d += 4) {
    float4 qv = *(const float4*)&qs[m][d];
    float4 k0 = *(const float4*)&ks[n0 + 0][d];
    float4 k1 = *(const float4*)&ks[n0 + 1][d];
    float4 k2 = *(const float4*)&ks[n0 + 2][d];
    float4 k3 = *(const float4*)&ks[n0 + 3][d];
    d0 += qv.x * k0.x + qv.y * k0.y + qv.z * k0.z + qv.w * k0.w;
    d1 += qv.x * k1.x + qv.y * k1.y + qv.z * k1.z + qv.w * k1.w;
    d2 += qv.x * k2.x + qv.y * k2.y + qv.z * k2.z + qv.w * k2.w;
    d3 += qv.x * k3.x + qv.y * k3.y + qv.z * k3.z + qv.w * k3.w;
  }
  int gm = mt + m;
  int gn = nt + n0;
  d0 *= 0.125f; d1 *= 0.125f; d2 *= 0.125f; d3 *= 0.125f;
  float mm = mask[b * SS + gm];
  float mn0 = mask[b * SS + gn + 0];
  float mn1 = mask[b * SS + gn + 1];
  float mn2 = mask[b * SS + gn + 2];
  float mn3 = mask[b * SS + gn + 3];
  const float* bmp = bias2 + (size_t)(b * SS + gm) * 24;
  const float* bnp0 = bias2 + (size_t)(b * SS + gn + 0) * 24;
  const float* bnp1 = bias2 + (size_t)(b * SS + gn + 1) * 24;
  const float* bnp2 = bias2 + (size_t)(b * SS + gn + 2) * 24;
  const float* bnp3 = bias2 + (size_t)(b * SS + gn + 3) * 24;
#pragma unroll
  for (int h = 0; h < NLH; ++h) {
    float tb = bmp[2 * h + 1];
    float v0 = d0 + bnp0[2 * h] + tb;
    float v1 = d1 + bnp1[2 * h] + tb;
    float v2 = d2 + bnp2[2 * h] + tb;
    float v3 = d3 + bnp3[2 * h] + tb;
    v0 = v0 * mm + NEGV * (1.f - mm); v1 = v1 * mm + NEGV * (1.f - mm);
    v2 = v2 * mm + NEGV * (1.f - mm); v3 = v3 * mm + NEGV * (1.f - mm);
    v0 = v0 * mn0 + NEGV * (1.f - mn0); v1 = v1 * mn1 + NEGV * (1.f - mn1);
    v2 = v2 * mn2 + NEGV * (1.f - mn2); v3 = v3 * mn3 + NEGV * (1.f - mn3);
    if (gm > gn + 0) v0 -= 1000000000000.0f;
    if (gm > gn + 1) v1 -= 1000000000000.0f;
    if (gm > gn + 2) v2 -= 1000000000000.0f;
    if (gm > gn + 3) v3 -= 1000000000000.0f;
    float4 o = make_float4(v0, v1, v2, v3);
    *(float4*)(out + ((((size_t)(b * NLH + h)) * SS + gm) * SS + gn)) = o;
  }
}

extern "C" void kernel_launch(void* const* d_in, const int* in_sizes, int n_in,
                              void* d_out, int out_size, void* d_ws, size_t ws_size,
                              hipStream_t stream)
{
  const float* bert    = (const float*)d_in[0];
  const float* amask   = (const float*)d_in[1];
  const float* dense_w = (const float*)d_in[2];
  const float* dense_b = (const float*)d_in[3];
  const float* sat_qw  = (const float*)d_in[4];
  const float* sat_qb  = (const float*)d_in[5];
  const float* sat_kw  = (const float*)d_in[6];
  const float* sat_kb  = (const float*)d_in[7];
  const float* sat_vw  = (const float*)d_in[8];
  const float* sat_vb  = (const float*)d_in[9];
  const float* sat_ow  = (const float*)d_in[10];
  const float* sat_ob  = (const float*)d_in[11];
  const float* rel_qw  = (const float*)d_in[12];
  const float* rel_qb  = (const float*)d_in[13];
  const float* rel_kw  = (const float*)d_in[14];
  const float* rel_kb  = (const float*)d_in[15];
  const float* rel_vw  = (const float*)d_in[16];
  const float* rel_vb  = (const float*)d_in[17];
  const float* rel_ow  = (const float*)d_in[18];
  const float* rel_ob  = (const float*)d_in[19];
  const float* lns_w   = (const float*)d_in[20];
  const float* lns_b   = (const float*)d_in[21];
  const float* lnr_w   = (const float*)d_in[22];
  const float* lnr_b   = (const float*)d_in[23];
  const float* head_w  = (const float*)d_in[24];
  const float* head_b  = (const float*)d_in[25];
  const float* tail_w  = (const float*)d_in[26];
  const float* tail_b  = (const float*)d_in[27];

  float* out = (float*)d_out;
  float* ws  = (float*)d_ws;

  const size_t NH = (size_t)BSROWS * HH; // 3145728
  float* hidden0 = ws;
  float* csA     = ws + NH;
  float* ctx     = ws + 2 * NH;
  float* sm      = ws + 3 * NH;
  float* center  = sm + 0 * 6144;
  float* center2 = sm + 1 * 6144;
  float* Kcen    = sm + 2 * 6144;
  float* Vcen    = sm + 3 * 6144;
  float* Qr      = sm + 4 * 6144;
  float* Krc     = sm + 5 * 6144;
  float* Vrc     = sm + 6 * 6144;
  float* ctxr    = sm + 7 * 6144;
  float* relo    = sm + 8 * 6144;
  float* outputs = sm + 9 * 6144;
  float* bias2   = outputs + (size_t)BSROWS * 128;
  float* qwbuf   = bias2 + (size_t)BSROWS * 24;
  float* kwbuf   = qwbuf + (size_t)BSROWS * 64;

  // d_out used as scratch until the final kernel overwrites it completely
  float* Kh0  = out;
  float* Vh0  = out + NH;
  float* Qbuf = out + 2 * NH;
  float* Kbuf = out + 3 * NH;

  dim3 blk(256);
  dim3 g768(12, 64);

  // hidden0 = bert @ dense_w + dense_b
  gemm_f32<<<g768, blk, 0, stream>>>(bert, dense_w, dense_b, nullptr, hidden0, BSROWS, HH, 432);
  // center = mean_s hidden0
  mean_kernel<<<24, 256, 0, stream>>>(hidden0, center);
  // sat K/V of hidden0 (also serves as iter-1 K/V of cs)
  gemm_f32<<<g768, blk, 0, stream>>>(hidden0, sat_kw, sat_kb, nullptr, Kh0, BSROWS, HH, HH);
  gemm_f32<<<g768, blk, 0, stream>>>(hidden0, sat_vw, sat_vb, nullptr, Vh0, BSROWS, HH, HH);

  // ---- iter 1 (cs = hidden0) ----
  gemm_f32<<<g768, blk, 0, stream>>>(hidden0, sat_qw, sat_qb, nullptr, Qbuf, BSROWS, HH, HH);
  {
    SmallJobs jobs;
    jobs.j[0] = { sat_kw, sat_kb, nullptr, Kcen };
    jobs.j[1] = { sat_vw, sat_vb, nullptr, Vcen };
    jobs.j[2] = { rel_qw, rel_qb, nullptr, Qr };
    jobs.j[3] = { rel_kw, rel_kb, nullptr, Krc };
    jobs.j[4] = { rel_vw, rel_vb, nullptr, Vrc };
    gemm_skinny<<<dim3(24, 5), blk, 0, stream>>>(center, jobs);
  }
  sat_attn<<<BSROWS, 256, 0, stream>>>(Qbuf, Kh0, Vh0, Kh0, Vh0, Kcen, Vcen, ctx);
  gemm_f32<<<g768, blk, 0, stream>>>(ctx, sat_ow, sat_ob, hidden0, Kbuf, BSROWS, HH, HH);
  relu_ln<<<BSROWS, 256, 0, stream>>>(Kbuf, lns_w, lns_b, csA);
  // rel branch (iter-2 center is dead, so only iter-1 needed)
  gemm_f32<<<g768, blk, 0, stream>>>(csA, rel_kw, rel_kb, nullptr, Qbuf, BSROWS, HH, HH); // Kr
  gemm_f32<<<g768, blk, 0, stream>>>(csA, rel_vw, rel_vb, nullptr, ctx, BSROWS, HH, HH);  // Vr
  rel_attn<<<dim3(8, 12), 256, 0, stream>>>(Qr, Krc, Qbuf, Vrc, ctx, ctxr);
  {
    SmallJobs jobs;
    jobs.j[0] = { rel_ow, rel_ob, center, relo };
    gemm_skinny<<<dim3(24, 1), blk, 0, stream>>>(ctxr, jobs);
  }
  relu_ln<<<8, 256, 0, stream>>>(relo, lnr_w, lnr_b, center2);

  // ---- iter 2 (cs = csA, center = center2) ----
  gemm_f32<<<g768, blk, 0, stream>>>(csA, sat_qw, sat_qb, nullptr, Qbuf, BSROWS, HH, HH);
  gemm_f32<<<g768, blk, 0, stream>>>(csA, sat_kw, sat_kb, nullptr, Kbuf, BSROWS, HH, HH);
  gemm_f32<<<g768, blk, 0, stream>>>(csA, sat_vw, sat_vb, nullptr, hidden0, BSROWS, HH, HH); // Vc2
  {
    SmallJobs jobs;
    jobs.j[0] = { sat_kw, sat_kb, nullptr, Kcen };
    jobs.j[1] = { sat_vw, sat_vb, nullptr, Vcen };
    gemm_skinny<<<dim3(24, 2), blk, 0, stream>>>(center2, jobs);
  }
  sat_attn<<<BSROWS, 256, 0, stream>>>(Qbuf, Kbuf, hidden0, Kh0, Vh0, Kcen, Vcen, ctx);
  gemm_f32<<<g768, blk, 0, stream>>>(ctx, sat_ow, sat_ob, csA, Qbuf, BSROWS, HH, HH);
  relu_ln<<<BSROWS, 256, 0, stream>>>(Qbuf, lns_w, lns_b, csA);

  // ---- head / rope / logits ----
  gemm_f32<<<dim3(2, 64), blk, 0, stream>>>(csA, head_w, head_b, nullptr, outputs, BSROWS, 128, HH);
  tail_gemm<<<384, 256, 0, stream>>>(outputs, tail_w, tail_b, bias2);
  rope_kernel<<<512, 256, 0, stream>>>(outputs, qwbuf, kwbuf);
  final_kernel<<<dim3(16, 16, 8), 256, 0, stream>>>(qwbuf, kwbuf, bias2, amask, out);
}

// Round 3
// 363.645 us; speedup vs baseline: 6.7198x; 2.8477x over previous
//
#include <hip/hip_runtime.h>
#include <cstdint>
#include <cstddef>

#define HH 768
#define SS 512
#define NBATCH 8
#define NLH 12
#define HDIM 64
#define BSROWS 4096
static constexpr float NEGV = -1000000000000.0f;

typedef unsigned short ushort_t;
typedef __attribute__((ext_vector_type(4))) float fx4;
typedef __attribute__((ext_vector_type(8))) short sx8;

__device__ __forceinline__ ushort_t f2bf(float f) {
  uint32_t u = __float_as_uint(f);
  uint32_t r = (u + 0x7FFFu + ((u >> 16) & 1u)) >> 16;
  return (ushort_t)r;
}
__device__ __forceinline__ float bf2f(ushort_t h) {
  return __uint_as_float(((uint32_t)h) << 16);
}

__device__ __forceinline__ void async_copy16(void* lds, const void* g) {
  __builtin_amdgcn_global_load_lds(
      (const __attribute__((address_space(1))) void*)g,
      (__attribute__((address_space(3))) void*)lds, 16, 0, 0);
}

// ============ bf16 MFMA GEMM: C[M,N] = A[M,K](bf16) @ Wt[N,K](bf16)^T + bias
// tile 128x128, BK=64, 4 waves. A,Wt K-contiguous. M%128==0, N%128==0, K%64==0.
__global__ __launch_bounds__(256) void gemm_bf16(
    const ushort_t* __restrict__ A, int lda,
    const ushort_t* __restrict__ B, int ldb,
    const float* __restrict__ bias,
    const ushort_t* __restrict__ resb,   // optional bf16 residual [.,ldo]
    float* __restrict__ C,               // optional f32 out [.,ldo]
    ushort_t* __restrict__ Cb,           // optional bf16 out [.,ldo]
    int ldo, int K)
{
  __shared__ ushort_t As[128 * 64];
  __shared__ ushort_t Bs[128 * 64];
  const int tid = threadIdx.x;
  const int bm = blockIdx.y * 128;
  const int bn = blockIdx.x * 128;
  const int l = tid & 63;
  const int w = tid >> 6;
  const int wr = w >> 1, wc = w & 1;
  const int r8 = tid >> 3;   // 0..31
  const int sl = tid & 7;    // 16B slot in 128B row

  fx4 acc[4][4];
#pragma unroll
  for (int m = 0; m < 4; ++m)
#pragma unroll
    for (int n = 0; n < 4; ++n) acc[m][n] = (fx4)0.f;

  for (int k0 = 0; k0 < K; k0 += 64) {
#pragma unroll
    for (int i = 0; i < 4; ++i) {
      int row = i * 32 + r8;
      int srcs = sl ^ (row & 7);
      async_copy16((char*)As + i * 4096 + tid * 16,
                   A + (size_t)(bm + row) * lda + k0 + srcs * 8);
    }
#pragma unroll
    for (int i = 0; i < 4; ++i) {
      int row = i * 32 + r8;
      int srcs = sl ^ (row & 7);
      async_copy16((char*)Bs + i * 4096 + tid * 16,
                   B + (size_t)(bn + row) * ldb + k0 + srcs * 8);
    }
    __syncthreads();
#pragma unroll
    for (int kk = 0; kk < 2; ++kk) {
      sx8 av[4], bv[4];
      const int so = (l >> 4) + kk * 4;
#pragma unroll
      for (int m = 0; m < 4; ++m) {
        int r = wr * 64 + m * 16 + (l & 15);
        av[m] = *(const sx8*)((const char*)As + r * 128 + ((so ^ (r & 7)) * 16));
      }
#pragma unroll
      for (int n = 0; n < 4; ++n) {
        int r = wc * 64 + n * 16 + (l & 15);
        bv[n] = *(const sx8*)((const char*)Bs + r * 128 + ((so ^ (r & 7)) * 16));
      }
#pragma unroll
      for (int m = 0; m < 4; ++m)
#pragma unroll
        for (int n = 0; n < 4; ++n)
          acc[m][n] = __builtin_amdgcn_mfma_f32_16x16x32_bf16(av[m], bv[n], acc[m][n], 0, 0, 0);
    }
    __syncthreads();
  }

  const int cr0 = bm + wr * 64 + (l >> 4) * 4;
  const int cc0 = bn + wc * 64 + (l & 15);
#pragma unroll
  for (int m = 0; m < 4; ++m) {
#pragma unroll
    for (int n = 0; n < 4; ++n) {
      int col = cc0 + n * 16;
      float bcol = bias[col];
#pragma unroll
      for (int j = 0; j < 4; ++j) {
        int row = cr0 + m * 16 + j;
        size_t off = (size_t)row * ldo + col;
        float v = acc[m][n][j] + bcol;
        if (resb) v += bf2f(resb[off]);
        if (C) C[off] = v;
        if (Cb) Cb[off] = f2bf(v);
      }
    }
  }
}

// ============ weight transpose+convert: Wt[rowOff+n][k] = bf16(W[k][n]), zero-pad k>=K
struct TJob { const float* src; ushort_t* dst; int K, N, Kpad, rowOff; };
struct TJobs { TJob j[8]; };
__global__ __launch_bounds__(256) void transpose_weights(TJobs jobs)
{
  TJob jb = jobs.j[blockIdx.z];
  int k0 = blockIdx.x * 32, n0 = blockIdx.y * 32;
  if (k0 >= jb.Kpad || n0 >= jb.N) return;
  __shared__ float t[32][33];
  int tx = threadIdx.x & 31, ty = threadIdx.x >> 5;  // 32x8
#pragma unroll
  for (int i = 0; i < 4; ++i) {
    int k = k0 + ty + i * 8;
    float v = 0.f;
    if (k < jb.K && n0 + tx < jb.N) v = jb.src[(size_t)k * jb.N + n0 + tx];
    t[ty + i * 8][tx] = v;
  }
  __syncthreads();
#pragma unroll
  for (int i = 0; i < 4; ++i) {
    int n = n0 + ty + i * 8;
    int k = k0 + tx;
    if (n < jb.N && k < jb.Kpad)
      jb.dst[(size_t)(jb.rowOff + n) * jb.Kpad + k] = f2bf(t[tx][ty + i * 8]);
  }
}

// ============ misc prep: bert->bf16 (K padded 432->448), bias concats
__global__ void prep_misc(const float* __restrict__ bert,
                          const float* __restrict__ sqb, const float* __restrict__ skb,
                          const float* __restrict__ svb,
                          const float* __restrict__ rkb, const float* __restrict__ rvb,
                          ushort_t* __restrict__ bert_bf,
                          float* __restrict__ b_satqkv, float* __restrict__ b_relkv)
{
  int i = blockIdx.x * 256 + threadIdx.x;
  const int NB = BSROWS * 448;
  if (i < NB) {
    int r = i / 448, c = i % 448;
    bert_bf[i] = (c < 432) ? f2bf(bert[(size_t)r * 432 + c]) : (ushort_t)0;
  } else if (i < NB + 2304) {
    int c = i - NB;
    b_satqkv[c] = (c < 768) ? sqb[c] : (c < 1536 ? skb[c - 768] : svb[c - 1536]);
  } else if (i < NB + 2304 + 1536) {
    int c = i - NB - 2304;
    b_relkv[c] = (c < 768) ? rkb[c] : rvb[c - 768];
  }
}

// ============ center = mean over s (bf16 input)
__global__ void mean_bf(const ushort_t* __restrict__ h0, float* __restrict__ center)
{
  int idx = blockIdx.x * blockDim.x + threadIdx.x;
  if (idx >= NBATCH * HH) return;
  int b = idx / HH, h = idx % HH;
  const ushort_t* p = h0 + (size_t)b * SS * HH + h;
  float s = 0.f;
  for (int i = 0; i < SS; ++i) s += bf2f(p[(size_t)i * HH]);
  center[idx] = s * (1.0f / SS);
}

// ============ skinny GEMM: M=8, K=768, N=768 (f32 weights), multi-job
struct SmallJob { const float* W; const float* bias; const float* res; float* C; };
struct SmallJobs { SmallJob j[5]; };
__global__ __launch_bounds__(256) void gemm_skinny(
    const float* __restrict__ A, SmallJobs jobs)
{
  __shared__ float As[8 * HH];
  __shared__ float part[8 * 8 * 32];
  const int tid = threadIdx.x;
  const SmallJob job = jobs.j[blockIdx.y];
#pragma unroll
  for (int i = 0; i < 6; ++i) {
    int idx = tid * 4 + i * 1024;
    *(float4*)&As[idx] = *(const float4*)(A + idx);
  }
  __syncthreads();
  const int c = tid & 31;
  const int col = (blockIdx.x << 5) + c;
  const int ks = tid >> 5;
  const float* Wp = job.W + (size_t)(ks * 96) * HH + col;
  float acc[8] = {};
#pragma unroll 8
  for (int k = 0; k < 96; ++k) {
    float wv = Wp[(size_t)k * HH];
    const float* ap = &As[ks * 96 + k];
#pragma unroll
    for (int m = 0; m < 8; ++m)
      acc[m] = fmaf(ap[m * HH], wv, acc[m]);
  }
#pragma unroll
  for (int m = 0; m < 8; ++m)
    part[ks * 256 + m * 32 + c] = acc[m];
  __syncthreads();
  const int m = tid >> 5;
  const int c2 = tid & 31;
  float s = 0.f;
#pragma unroll
  for (int k = 0; k < 8; ++k) s += part[k * 256 + m * 32 + c2];
  const int outcol = (blockIdx.x << 5) + c2;
  float v = s + job.bias[outcol];
  if (job.res) v += job.res[(size_t)m * HH + outcol];
  job.C[(size_t)m * HH + outcol] = v;
}

// ============ star attention (f32 QKV with stride), bf16 ctx out
__global__ __launch_bounds__(256) void sat_attn(
    const float* __restrict__ Qc, const float* __restrict__ Kc, const float* __restrict__ Vc, int ldq,
    const float* __restrict__ Kh0, const float* __restrict__ Vh0, int ldh,
    const float* __restrict__ Kcen, const float* __restrict__ Vcen,
    ushort_t* __restrict__ ctxb)
{
  int i = blockIdx.x;
  int b = i >> 9, s = i & 511;
  int lane = threadIdx.x & 63;
  int wave = threadIdx.x >> 6;
  size_t rb = (size_t)(b * SS + ((s + 1) & 511));
  size_t rs = (size_t)i;
  size_t ra = (size_t)(b * SS + (s == 0 ? (SS - 1) : 0));
  size_t rc = (size_t)b * HH;
  for (int h = wave; h < NLH; h += 4) {
    int off = h * HDIM + lane;
    float q = Qc[rs * ldq + off];
    float s0 = q * Kc[rb * ldq + off];
    float s1 = q * Kc[rs * ldq + off];
    float s2 = q * Kc[ra * ldq + off];
    float s3 = q * Kh0[rs * ldh + off];
    float s4 = q * Kcen[rc + off];
#pragma unroll
    for (int d = 1; d < 64; d <<= 1) {
      s0 += __shfl_xor(s0, d); s1 += __shfl_xor(s1, d); s2 += __shfl_xor(s2, d);
      s3 += __shfl_xor(s3, d); s4 += __shfl_xor(s4, d);
    }
    const float sc = 0.125f;
    s0 *= sc; s1 *= sc; s2 *= sc; s3 *= sc; s4 *= sc;
    float mx = fmaxf(fmaxf(fmaxf(s0, s1), fmaxf(s2, s3)), s4);
    float e0 = __expf(s0 - mx), e1 = __expf(s1 - mx), e2 = __expf(s2 - mx);
    float e3 = __expf(s3 - mx), e4 = __expf(s4 - mx);
    float inv = 1.f / (e0 + e1 + e2 + e3 + e4);
    float v = e0 * Vc[rb * ldq + off] + e1 * Vc[rs * ldq + off] + e2 * Vc[ra * ldq + off]
            + e3 * Vh0[rs * ldh + off] + e4 * Vcen[rc + off];
    ctxb[rs * HH + off] = f2bf(v * inv);
  }
}

// ============ relu + layernorm, optional f32/bf16 outs
__global__ __launch_bounds__(256) void relu_ln(
    const float* __restrict__ x, const float* __restrict__ w, const float* __restrict__ b,
    float* __restrict__ y32, ushort_t* __restrict__ ybf)
{
  int row = blockIdx.x;
  const float* xr = x + (size_t)row * HH;
  float v[3];
  float sum = 0.f, sumsq = 0.f;
#pragma unroll
  for (int j = 0; j < 3; ++j) {
    float t = xr[threadIdx.x + j * 256];
    t = fmaxf(t, 0.f);
    v[j] = t;
    sum += t; sumsq += t * t;
  }
#pragma unroll
  for (int d = 1; d < 64; d <<= 1) { sum += __shfl_xor(sum, d); sumsq += __shfl_xor(sumsq, d); }
  __shared__ float ws_[4], wsq_[4];
  int wave = threadIdx.x >> 6, lane = threadIdx.x & 63;
  if (lane == 0) { ws_[wave] = sum; wsq_[wave] = sumsq; }
  __syncthreads();
  sum = ws_[0] + ws_[1] + ws_[2] + ws_[3];
  sumsq = wsq_[0] + wsq_[1] + wsq_[2] + wsq_[3];
  float mean = sum * (1.0f / HH);
  float var = sumsq * (1.0f / HH) - mean * mean;
  float rstd = rsqrtf(var + 1e-12f);
#pragma unroll
  for (int j = 0; j < 3; ++j) {
    int cidx = threadIdx.x + j * 256;
    float o = w[cidx] * (v[j] - mean) * rstd + b[cidx];
    if (y32) y32[(size_t)row * HH + cidx] = o;
    if (ybf) ybf[(size_t)row * HH + cidx] = f2bf(o);
  }
}

// ============ rel attention: Kr/Vr strided
__global__ __launch_bounds__(256) void rel_attn(
    const float* __restrict__ Qr, const float* __restrict__ Krc, const float* __restrict__ Kr,
    const float* __restrict__ Vrc, const float* __restrict__ Vr, int ldkv,
    float* __restrict__ ctx)
{
  int b = blockIdx.x, h = blockIdx.y;
  __shared__ float qs[64];
  __shared__ float sc[513];
  __shared__ float part[4][64];
  __shared__ float redm[4], redsum[4];
  int t = threadIdx.x, lane = t & 63, wave = t >> 6;
  if (t < 64) qs[t] = Qr[b * HH + h * HDIM + t];
  __syncthreads();
  for (int j = t; j < 513; j += 256) {
    const float* kp = (j == 0) ? (Krc + b * HH + h * HDIM)
                               : (Kr + (size_t)(b * SS + j - 1) * ldkv + h * HDIM);
    float acc = 0.f;
    for (int d = 0; d < HDIM; ++d) acc = fmaf(qs[d], kp[d], acc);
    sc[j] = acc * 0.125f;
  }
  __syncthreads();
  float m = -1e30f;
  for (int j = t; j < 513; j += 256) m = fmaxf(m, sc[j]);
#pragma unroll
  for (int d = 1; d < 64; d <<= 1) m = fmaxf(m, __shfl_xor(m, d));
  if (lane == 0) redm[wave] = m;
  __syncthreads();
  m = fmaxf(fmaxf(redm[0], redm[1]), fmaxf(redm[2], redm[3]));
  float lsum = 0.f;
  for (int j = t; j < 513; j += 256) { float e = __expf(sc[j] - m); sc[j] = e; lsum += e; }
#pragma unroll
  for (int d = 1; d < 64; d <<= 1) lsum += __shfl_xor(lsum, d);
  if (lane == 0) redsum[wave] = lsum;
  __syncthreads();
  float total = redsum[0] + redsum[1] + redsum[2] + redsum[3];
  float accv = 0.f;
  for (int j = wave; j < 513; j += 4) {
    const float* vp = (j == 0) ? (Vrc + b * HH + h * HDIM)
                               : (Vr + (size_t)(b * SS + j - 1) * ldkv + h * HDIM);
    accv = fmaf(sc[j], vp[lane], accv);
  }
  part[wave][lane] = accv;
  __syncthreads();
  if (wave == 0) {
    float r = (part[0][lane] + part[1][lane] + part[2][lane] + part[3][lane]) / total;
    ctx[b * HH + h * HDIM + lane] = r;
  }
}

// ============ tail: bias2[row,c] = (outputs[row,:] @ tail_w + tail_b)[c] * 0.5
__global__ void tail_gemm(const float* __restrict__ A, const float* __restrict__ W,
                          const float* __restrict__ bias, float* __restrict__ C)
{
  int idx = blockIdx.x * blockDim.x + threadIdx.x;
  if (idx >= BSROWS * 24) return;
  int row = idx / 24, c = idx % 24;
  float acc = bias[c];
  const float* a = A + (size_t)row * 128;
  for (int k = 0; k < 128; ++k) acc = fmaf(a[k], W[k * 24 + c], acc);
  C[idx] = acc * 0.5f;
}

// ============ RoPE split
__global__ void rope_kernel(const float* __restrict__ outputs,
                            float* __restrict__ qw, float* __restrict__ kw)
{
  int idx = blockIdx.x * blockDim.x + threadIdx.x;
  if (idx >= BSROWS * 32) return;
  int row = idx >> 5;
  int i = idx & 31;
  int s = row & 511;
  float inv = powf(10000.0f, -2.0f * (float)i / 64.0f);
  float ang = (float)s * inv;
  float sn = sinf(ang), cn = cosf(ang);
  const float* o = outputs + (size_t)row * 128 + i * 4;
  float q0 = o[0], k0 = o[1], q1 = o[2], k1 = o[3];
  float* qp = qw + (size_t)row * 64 + i * 2;
  float* kp = kw + (size_t)row * 64 + i * 2;
  qp[0] = q0 * cn - q1 * sn; qp[1] = q1 * cn + q0 * sn;
  kp[0] = k0 * cn - k1 * sn; kp[1] = k1 * cn + k0 * sn;
}

// ============ final logits
__global__ __launch_bounds__(256) void final_kernel(
    const float* __restrict__ qw, const float* __restrict__ kw,
    const float* __restrict__ bias2, const float* __restrict__ mask,
    float* __restrict__ out)
{
  int b = blockIdx.z;
  int mt = blockIdx.y * 32;
  int nt = blockIdx.x * 32;
  __shared__ float qs[32][68];
  __shared__ float ks[32][68];
  int t = threadIdx.x;
  {
    int idx = t * 8;
    int r = idx >> 6, c = idx & 63;
    const float* sq = qw + (size_t)(b * SS + mt + r) * 64 + c;
    const float* sk = kw + (size_t)(b * SS + nt + r) * 64 + c;
    *(float4*)&qs[r][c]     = *(const float4*)(sq);
    *(float4*)&qs[r][c + 4] = *(const float4*)(sq + 4);
    *(float4*)&ks[r][c]     = *(const float4*)(sk);
    *(float4*)&ks[r][c + 4] = *(const float4*)(sk + 4);
  }
  __syncthreads();
  int m = t >> 3;
  int n0 = (t & 7) * 4;
  float d0 = 0.f, d1 = 0.f, d2 = 0.f, d3 = 0.f;
#pragma unroll
  for (int d = 0; d < 64; d += 4) {
    float4 qv = *(const float4*)&qs[m][d];
    float4 k0 = *(const float4*)&ks[n0 + 0][d];
    float4 k1 = *(const float4*)&ks[n0 + 1][d];
    float4 k2 = *(const float4*)&ks[n0 + 2][d];
    float4 k3 = *(const float4*)&ks[n0 + 3][d];
    d0 += qv.x * k0.x + qv.y * k0.y + qv.z * k0.z + qv.w * k0.w;
    d1 += qv.x * k1.x + qv.y * k1.y + qv.z * k1.z + qv.w * k1.w;
    d2 += qv.x * k2.x + qv.y * k2.y + qv.z * k2.z + qv.w * k2.w;
    d3 += qv.x * k3.x + qv.y * k3.y + qv.z * k3.z + qv.w * k3.w;
  }
  int gm = mt + m;
  int gn = nt + n0;
  d0 *= 0.125f; d1 *= 0.125f; d2 *= 0.125f; d3 *= 0.125f;
  float mm = mask[b * SS + gm];
  float mn0 = mask[b * SS + gn + 0];
  float mn1 = mask[b * SS + gn + 1];
  float mn2 = mask[b * SS + gn + 2];
  float mn3 = mask[b * SS + gn + 3];
  const float* bmp  = bias2 + (size_t)(b * SS + gm) * 24;
  const float* bnp0 = bias2 + (size_t)(b * SS + gn + 0) * 24;
  const float* bnp1 = bias2 + (size_t)(b * SS + gn + 1) * 24;
  const float* bnp2 = bias2 + (size_t)(b * SS + gn + 2) * 24;
  const float* bnp3 = bias2 + (size_t)(b * SS + gn + 3) * 24;
#pragma unroll
  for (int h = 0; h < NLH; ++h) {
    float tb = bmp[2 * h + 1];
    float v0 = d0 + bnp0[2 * h] + tb;
    float v1 = d1 + bnp1[2 * h] + tb;
    float v2 = d2 + bnp2[2 * h] + tb;
    float v3 = d3 + bnp3[2 * h] + tb;
    v0 = v0 * mm + NEGV * (1.f - mm); v1 = v1 * mm + NEGV * (1.f - mm);
    v2 = v2 * mm + NEGV * (1.f - mm); v3 = v3 * mm + NEGV * (1.f - mm);
    v0 = v0 * mn0 + NEGV * (1.f - mn0); v1 = v1 * mn1 + NEGV * (1.f - mn1);
    v2 = v2 * mn2 + NEGV * (1.f - mn2); v3 = v3 * mn3 + NEGV * (1.f - mn3);
    if (gm > gn + 0) v0 -= 1000000000000.0f;
    if (gm > gn + 1) v1 -= 1000000000000.0f;
    if (gm > gn + 2) v2 -= 1000000000000.0f;
    if (gm > gn + 3) v3 -= 1000000000000.0f;
    float4 o = make_float4(v0, v1, v2, v3);
    *(float4*)(out + ((((size_t)(b * NLH + h)) * SS + gm) * SS + gn)) = o;
  }
}

extern "C" void kernel_launch(void* const* d_in, const int* in_sizes, int n_in,
                              void* d_out, int out_size, void* d_ws, size_t ws_size,
                              hipStream_t stream)
{
  const float* bert    = (const float*)d_in[0];
  const float* amask   = (const float*)d_in[1];
  const float* dense_w = (const float*)d_in[2];
  const float* dense_b = (const float*)d_in[3];
  const float* sat_qw  = (const float*)d_in[4];
  const float* sat_qb  = (const float*)d_in[5];
  const float* sat_kw  = (const float*)d_in[6];
  const float* sat_kb  = (const float*)d_in[7];
  const float* sat_vw  = (const float*)d_in[8];
  const float* sat_vb  = (const float*)d_in[9];
  const float* sat_ow  = (const float*)d_in[10];
  const float* sat_ob  = (const float*)d_in[11];
  const float* rel_qw  = (const float*)d_in[12];
  const float* rel_qb  = (const float*)d_in[13];
  const float* rel_kw  = (const float*)d_in[14];
  const float* rel_kb  = (const float*)d_in[15];
  const float* rel_vw  = (const float*)d_in[16];
  const float* rel_vb  = (const float*)d_in[17];
  const float* rel_ow  = (const float*)d_in[18];
  const float* rel_ob  = (const float*)d_in[19];
  const float* lns_w   = (const float*)d_in[20];
  const float* lns_b   = (const float*)d_in[21];
  const float* lnr_w   = (const float*)d_in[22];
  const float* lnr_b   = (const float*)d_in[23];
  const float* head_w  = (const float*)d_in[24];
  const float* head_b  = (const float*)d_in[25];
  const float* tail_w  = (const float*)d_in[26];
  const float* tail_b  = (const float*)d_in[27];

  float* out = (float*)d_out;
  char*  ws  = (char*)d_ws;

  // ---- ws carve-up (bf16 buffers + small f32) ----
  size_t off = 0;
  auto alloc = [&](size_t bytes) { char* p = ws + off; off += (bytes + 255) & ~(size_t)255; return p; };
  ushort_t* bert_bf   = (ushort_t*)alloc((size_t)BSROWS * 448 * 2);
  ushort_t* Wt_dense  = (ushort_t*)alloc((size_t)768 * 448 * 2);
  ushort_t* Wt_satqkv = (ushort_t*)alloc((size_t)2304 * 768 * 2);
  ushort_t* Wt_satow  = (ushort_t*)alloc((size_t)768 * 768 * 2);
  ushort_t* Wt_relkv  = (ushort_t*)alloc((size_t)1536 * 768 * 2);
  ushort_t* Wt_head   = (ushort_t*)alloc((size_t)128 * 768 * 2);
  ushort_t* hidden0_bf= (ushort_t*)alloc((size_t)BSROWS * HH * 2);
  ushort_t* ctx_bf    = (ushort_t*)alloc((size_t)BSROWS * HH * 2);
  ushort_t* csA_bf    = (ushort_t*)alloc((size_t)BSROWS * HH * 2);
  float* b_satqkv = (float*)alloc(2304 * 4);
  float* b_relkv  = (float*)alloc(1536 * 4);
  float* center   = (float*)alloc(6144 * 4);
  float* center2  = (float*)alloc(6144 * 4);
  float* Kcen     = (float*)alloc(6144 * 4);
  float* Vcen     = (float*)alloc(6144 * 4);
  float* Qr       = (float*)alloc(6144 * 4);
  float* Krc      = (float*)alloc(6144 * 4);
  float* Vrc      = (float*)alloc(6144 * 4);
  float* ctxr     = (float*)alloc(6144 * 4);
  float* relo     = (float*)alloc(6144 * 4);
  float* outputs  = (float*)alloc((size_t)BSROWS * 128 * 4);
  float* bias2    = (float*)alloc((size_t)BSROWS * 24 * 4);
  float* qwbuf    = (float*)alloc((size_t)BSROWS * 64 * 4);
  float* kwbuf    = (float*)alloc((size_t)BSROWS * 64 * 4);

  // ---- d_out as scratch (fully overwritten by final_kernel) ----
  // QKV1: [4096][2304] f32 at out+0; region2 at out+9437184 (15.7M floats)
  float* QKV1    = out;
  float* region2 = out + (size_t)BSROWS * 2304;
  float* tmp1    = region2;                 // [4096][768], dead before KrVr
  float* KrVr    = region2;                 // [4096][1536], dead before QKV2
  float* QKV2    = region2;                 // [4096][2304]
  float* tmp2    = QKV1;                    // [4096][768], after QKV1 dead

  dim3 blk(256);

  // ---- prep ----
  {
    TJobs tj;
    tj.j[0] = { dense_w, Wt_dense,  432, 768, 448, 0 };
    tj.j[1] = { sat_qw,  Wt_satqkv, 768, 768, 768, 0 };
    tj.j[2] = { sat_kw,  Wt_satqkv, 768, 768, 768, 768 };
    tj.j[3] = { sat_vw,  Wt_satqkv, 768, 768, 768, 1536 };
    tj.j[4] = { sat_ow,  Wt_satow,  768, 768, 768, 0 };
    tj.j[5] = { rel_kw,  Wt_relkv,  768, 768, 768, 0 };
    tj.j[6] = { rel_vw,  Wt_relkv,  768, 768, 768, 768 };
    tj.j[7] = { head_w,  Wt_head,   768, 128, 768, 0 };
    transpose_weights<<<dim3(24, 24, 8), blk, 0, stream>>>(tj);
  }
  {
    int total = BSROWS * 448 + 2304 + 1536;
    prep_misc<<<(total + 255) / 256, blk, 0, stream>>>(
        bert, sat_qb, sat_kb, sat_vb, rel_kb, rel_vb, bert_bf, b_satqkv, b_relkv);
  }

  // ---- dense: hidden0_bf = bf16(bert @ dense_w + dense_b) ----
  gemm_bf16<<<dim3(6, 32), blk, 0, stream>>>(bert_bf, 448, Wt_dense, 448, dense_b,
                                             nullptr, nullptr, hidden0_bf, HH, 448);
  mean_bf<<<24, 256, 0, stream>>>(hidden0_bf, center);

  // ---- iter 1 ----
  gemm_bf16<<<dim3(18, 32), blk, 0, stream>>>(hidden0_bf, HH, Wt_satqkv, HH, b_satqkv,
                                              nullptr, QKV1, nullptr, 2304, HH);
  {
    SmallJobs jobs;
    jobs.j[0] = { sat_kw, sat_kb, nullptr, Kcen };
    jobs.j[1] = { sat_vw, sat_vb, nullptr, Vcen };
    jobs.j[2] = { rel_qw, rel_qb, nullptr, Qr };
    jobs.j[3] = { rel_kw, rel_kb, nullptr, Krc };
    jobs.j[4] = { rel_vw, rel_vb, nullptr, Vrc };
    gemm_skinny<<<dim3(24, 5), blk, 0, stream>>>(center, jobs);
  }
  sat_attn<<<BSROWS, 256, 0, stream>>>(QKV1, QKV1 + 768, QKV1 + 1536, 2304,
                                       QKV1 + 768, QKV1 + 1536, 2304,
                                       Kcen, Vcen, ctx_bf);
  gemm_bf16<<<dim3(6, 32), blk, 0, stream>>>(ctx_bf, HH, Wt_satow, HH, sat_ob,
                                             hidden0_bf, tmp1, nullptr, HH, HH);
  relu_ln<<<BSROWS, 256, 0, stream>>>(tmp1, lns_w, lns_b, nullptr, csA_bf);

  // rel branch (iter-2 center is dead, only iter-1 needed)
  gemm_bf16<<<dim3(12, 32), blk, 0, stream>>>(csA_bf, HH, Wt_relkv, HH, b_relkv,
                                              nullptr, KrVr, nullptr, 1536, HH);
  rel_attn<<<dim3(8, 12), 256, 0, stream>>>(Qr, Krc, KrVr, Vrc, KrVr + 768, 1536, ctxr);
  {
    SmallJobs jobs;
    jobs.j[0] = { rel_ow, rel_ob, center, relo };
    gemm_skinny<<<dim3(24, 1), blk, 0, stream>>>(ctxr, jobs);
  }
  relu_ln<<<8, 256, 0, stream>>>(relo, lnr_w, lnr_b, center2, nullptr);

  // ---- iter 2 ----
  gemm_bf16<<<dim3(18, 32), blk, 0, stream>>>(csA_bf, HH, Wt_satqkv, HH, b_satqkv,
                                              nullptr, QKV2, nullptr, 2304, HH);
  {
    SmallJobs jobs;
    jobs.j[0] = { sat_kw, sat_kb, nullptr, Kcen };
    jobs.j[1] = { sat_vw, sat_vb, nullptr, Vcen };
    gemm_skinny<<<dim3(24, 2), blk, 0, stream>>>(center2, jobs);
  }
  sat_attn<<<BSROWS, 256, 0, stream>>>(QKV2, QKV2 + 768, QKV2 + 1536, 2304,
                                       QKV1 + 768, QKV1 + 1536, 2304,
                                       Kcen, Vcen, ctx_bf);
  gemm_bf16<<<dim3(6, 32), blk, 0, stream>>>(ctx_bf, HH, Wt_satow, HH, sat_ob,
                                             csA_bf, tmp2, nullptr, HH, HH);
  relu_ln<<<BSROWS, 256, 0, stream>>>(tmp2, lns_w, lns_b, nullptr, csA_bf);

  // ---- head / rope / logits ----
  gemm_bf16<<<dim3(1, 32), blk, 0, stream>>>(csA_bf, HH, Wt_head, HH, head_b,
                                             nullptr, outputs, nullptr, 128, HH);
  tail_gemm<<<384, 256, 0, stream>>>(outputs, tail_w, tail_b, bias2);
  rope_kernel<<<512, 256, 0, stream>>>(outputs, qwbuf, kwbuf);
  final_kernel<<<dim3(16, 16, 8), 256, 0, stream>>>(qwbuf, kwbuf, bias2, amask, out);
}

// Round 4
// 356.539 us; speedup vs baseline: 6.8537x; 1.0199x over previous
//
#include <hip/hip_runtime.h>
#include <cstdint>
#include <cstddef>

#define HH 768
#define SS 512
#define NBATCH 8
#define NLH 12
#define HDIM 64
#define BSROWS 4096
static constexpr float NEGV = -1000000000000.0f;

typedef unsigned short ushort_t;
typedef __attribute__((ext_vector_type(4))) float fx4;
typedef __attribute__((ext_vector_type(8))) short sx8;

__device__ __forceinline__ ushort_t f2bf(float f) {
  uint32_t u = __float_as_uint(f);
  uint32_t r = (u + 0x7FFFu + ((u >> 16) & 1u)) >> 16;
  return (ushort_t)r;
}
__device__ __forceinline__ float bf2f(ushort_t h) {
  return __uint_as_float(((uint32_t)h) << 16);
}

__device__ __forceinline__ void async_copy16(void* lds, const void* g) {
  __builtin_amdgcn_global_load_lds(
      (const __attribute__((address_space(1))) void*)g,
      (__attribute__((address_space(3))) void*)lds, 16, 0, 0);
}

// ============ bf16 MFMA GEMM: C[M,N] = A[M,K](bf16) @ Wt[N,K](bf16)^T + bias
// tile 128x128, BK=64, 4 waves. A,Wt K-contiguous. M%128==0, N%128==0, K%64==0.
__global__ __launch_bounds__(256) void gemm_bf16(
    const ushort_t* __restrict__ A, int lda,
    const ushort_t* __restrict__ B, int ldb,
    const float* __restrict__ bias,
    const ushort_t* __restrict__ resb,   // optional bf16 residual [.,ldo]
    float* __restrict__ C,               // optional f32 out [.,ldo]
    ushort_t* __restrict__ Cb,           // optional bf16 out [.,ldo]
    int ldo, int K)
{
  __shared__ ushort_t As[128 * 64];
  __shared__ ushort_t Bs[128 * 64];
  const int tid = threadIdx.x;
  const int bm = blockIdx.y * 128;
  const int bn = blockIdx.x * 128;
  const int l = tid & 63;
  const int w = tid >> 6;
  const int wr = w >> 1, wc = w & 1;
  const int r8 = tid >> 3;   // 0..31
  const int sl = tid & 7;    // 16B slot in 128B row

  fx4 acc[4][4];
#pragma unroll
  for (int m = 0; m < 4; ++m)
#pragma unroll
    for (int n = 0; n < 4; ++n) acc[m][n] = (fx4)0.f;

  for (int k0 = 0; k0 < K; k0 += 64) {
#pragma unroll
    for (int i = 0; i < 4; ++i) {
      int row = i * 32 + r8;
      int srcs = sl ^ (row & 7);
      async_copy16((char*)As + i * 4096 + tid * 16,
                   A + (size_t)(bm + row) * lda + k0 + srcs * 8);
    }
#pragma unroll
    for (int i = 0; i < 4; ++i) {
      int row = i * 32 + r8;
      int srcs = sl ^ (row & 7);
      async_copy16((char*)Bs + i * 4096 + tid * 16,
                   B + (size_t)(bn + row) * ldb + k0 + srcs * 8);
    }
    __syncthreads();
#pragma unroll
    for (int kk = 0; kk < 2; ++kk) {
      sx8 av[4], bv[4];
      const int so = (l >> 4) + kk * 4;
#pragma unroll
      for (int m = 0; m < 4; ++m) {
        int r = wr * 64 + m * 16 + (l & 15);
        av[m] = *(const sx8*)((const char*)As + r * 128 + ((so ^ (r & 7)) * 16));
      }
#pragma unroll
      for (int n = 0; n < 4; ++n) {
        int r = wc * 64 + n * 16 + (l & 15);
        bv[n] = *(const sx8*)((const char*)Bs + r * 128 + ((so ^ (r & 7)) * 16));
      }
#pragma unroll
      for (int m = 0; m < 4; ++m)
#pragma unroll
        for (int n = 0; n < 4; ++n)
          acc[m][n] = __builtin_amdgcn_mfma_f32_16x16x32_bf16(av[m], bv[n], acc[m][n], 0, 0, 0);
    }
    __syncthreads();
  }

  const int cr0 = bm + wr * 64 + (l >> 4) * 4;
  const int cc0 = bn + wc * 64 + (l & 15);
#pragma unroll
  for (int m = 0; m < 4; ++m) {
#pragma unroll
    for (int n = 0; n < 4; ++n) {
      int col = cc0 + n * 16;
      float bcol = bias[col];
#pragma unroll
      for (int j = 0; j < 4; ++j) {
        int row = cr0 + m * 16 + j;
        size_t off = (size_t)row * ldo + col;
        float v = acc[m][n][j] + bcol;
        if (resb) v += bf2f(resb[off]);
        if (C) C[off] = v;
        if (Cb) Cb[off] = f2bf(v);
      }
    }
  }
}

// ============ weight transpose+convert: Wt[rowOff+n][k] = bf16(W[k][n]), zero-pad k>=K
struct TJob { const float* src; ushort_t* dst; int K, N, Kpad, rowOff; };
struct TJobs { TJob j[8]; };
__global__ __launch_bounds__(256) void transpose_weights(TJobs jobs)
{
  TJob jb = jobs.j[blockIdx.z];
  int k0 = blockIdx.x * 32, n0 = blockIdx.y * 32;
  if (k0 >= jb.Kpad || n0 >= jb.N) return;
  __shared__ float t[32][33];
  int tx = threadIdx.x & 31, ty = threadIdx.x >> 5;  // 32x8
#pragma unroll
  for (int i = 0; i < 4; ++i) {
    int k = k0 + ty + i * 8;
    float v = 0.f;
    if (k < jb.K && n0 + tx < jb.N) v = jb.src[(size_t)k * jb.N + n0 + tx];
    t[ty + i * 8][tx] = v;
  }
  __syncthreads();
#pragma unroll
  for (int i = 0; i < 4; ++i) {
    int n = n0 + ty + i * 8;
    int k = k0 + tx;
    if (n < jb.N && k < jb.Kpad)
      jb.dst[(size_t)(jb.rowOff + n) * jb.Kpad + k] = f2bf(t[tx][ty + i * 8]);
  }
}

// ============ misc prep: bert->bf16 (K padded 432->448), bias concats
__global__ void prep_misc(const float* __restrict__ bert,
                          const float* __restrict__ sqb, const float* __restrict__ skb,
                          const float* __restrict__ svb,
                          const float* __restrict__ rkb, const float* __restrict__ rvb,
                          ushort_t* __restrict__ bert_bf,
                          float* __restrict__ b_satqkv, float* __restrict__ b_relkv)
{
  int i = blockIdx.x * 256 + threadIdx.x;
  const int NB = BSROWS * 448;
  if (i < NB) {
    int r = i / 448, c = i % 448;
    bert_bf[i] = (c < 432) ? f2bf(bert[(size_t)r * 432 + c]) : (ushort_t)0;
  } else if (i < NB + 2304) {
    int c = i - NB;
    b_satqkv[c] = (c < 768) ? sqb[c] : (c < 1536 ? skb[c - 768] : svb[c - 1536]);
  } else if (i < NB + 2304 + 1536) {
    int c = i - NB - 2304;
    b_relkv[c] = (c < 768) ? rkb[c] : rvb[c - 768];
  }
}

// ============ center = mean over s (bf16 input), parallel: grid (6,8)
__global__ __launch_bounds__(256) void mean_bf(const ushort_t* __restrict__ h0,
                                               float* __restrict__ center)
{
  int b = blockIdx.y;
  int col = blockIdx.x * 128 + (threadIdx.x & 127);
  int half = threadIdx.x >> 7;
  const ushort_t* p = h0 + ((size_t)b * SS + half * 256) * HH + col;
  float s = 0.f;
#pragma unroll 8
  for (int i = 0; i < 256; ++i) s += bf2f(p[(size_t)i * HH]);
  __shared__ float red[2][128];
  red[half][threadIdx.x & 127] = s;
  __syncthreads();
  if (half == 0)
    center[b * HH + col] = (red[0][threadIdx.x] + red[1][threadIdx.x]) * (1.0f / 512.0f);
}

// ============ skinny GEMM: M=8, K=768, N=768 (f32 weights), multi-job
struct SmallJob { const float* W; const float* bias; const float* res; float* C; };
struct SmallJobs { SmallJob j[5]; };
__global__ __launch_bounds__(256) void gemm_skinny(
    const float* __restrict__ A, SmallJobs jobs)
{
  __shared__ float As[8 * HH];
  __shared__ float part[8 * 8 * 32];
  const int tid = threadIdx.x;
  const SmallJob job = jobs.j[blockIdx.y];
#pragma unroll
  for (int i = 0; i < 6; ++i) {
    int idx = tid * 4 + i * 1024;
    *(float4*)&As[idx] = *(const float4*)(A + idx);
  }
  __syncthreads();
  const int c = tid & 31;
  const int col = (blockIdx.x << 5) + c;
  const int ks = tid >> 5;
  const float* Wp = job.W + (size_t)(ks * 96) * HH + col;
  float acc[8] = {};
#pragma unroll 8
  for (int k = 0; k < 96; ++k) {
    float wv = Wp[(size_t)k * HH];
    const float* ap = &As[ks * 96 + k];
#pragma unroll
    for (int m = 0; m < 8; ++m)
      acc[m] = fmaf(ap[m * HH], wv, acc[m]);
  }
#pragma unroll
  for (int m = 0; m < 8; ++m)
    part[ks * 256 + m * 32 + c] = acc[m];
  __syncthreads();
  const int m = tid >> 5;
  const int c2 = tid & 31;
  float s = 0.f;
#pragma unroll
  for (int k = 0; k < 8; ++k) s += part[k * 256 + m * 32 + c2];
  const int outcol = (blockIdx.x << 5) + c2;
  float v = s + job.bias[outcol];
  if (job.res) v += job.res[(size_t)m * HH + outcol];
  job.C[(size_t)m * HH + outcol] = v;
}

// ============ star attention (bf16 QKV, strided), bf16 ctx out
__global__ __launch_bounds__(256) void sat_attn(
    const ushort_t* __restrict__ Qc, const ushort_t* __restrict__ Kc,
    const ushort_t* __restrict__ Vc, int ldq,
    const ushort_t* __restrict__ Kh0, const ushort_t* __restrict__ Vh0, int ldh,
    const float* __restrict__ Kcen, const float* __restrict__ Vcen,
    ushort_t* __restrict__ ctxb)
{
  int i = blockIdx.x;
  int b = i >> 9, s = i & 511;
  int lane = threadIdx.x & 63;
  int wave = threadIdx.x >> 6;
  size_t rb = (size_t)(b * SS + ((s + 1) & 511));
  size_t rs = (size_t)i;
  size_t ra = (size_t)(b * SS + (s == 0 ? (SS - 1) : 0));
  size_t rc = (size_t)b * HH;
  for (int h = wave; h < NLH; h += 4) {
    int off = h * HDIM + lane;
    float q = bf2f(Qc[rs * ldq + off]);
    float s0 = q * bf2f(Kc[rb * ldq + off]);
    float s1 = q * bf2f(Kc[rs * ldq + off]);
    float s2 = q * bf2f(Kc[ra * ldq + off]);
    float s3 = q * bf2f(Kh0[rs * ldh + off]);
    float s4 = q * Kcen[rc + off];
#pragma unroll
    for (int d = 1; d < 64; d <<= 1) {
      s0 += __shfl_xor(s0, d); s1 += __shfl_xor(s1, d); s2 += __shfl_xor(s2, d);
      s3 += __shfl_xor(s3, d); s4 += __shfl_xor(s4, d);
    }
    const float sc = 0.125f;
    s0 *= sc; s1 *= sc; s2 *= sc; s3 *= sc; s4 *= sc;
    float mx = fmaxf(fmaxf(fmaxf(s0, s1), fmaxf(s2, s3)), s4);
    float e0 = __expf(s0 - mx), e1 = __expf(s1 - mx), e2 = __expf(s2 - mx);
    float e3 = __expf(s3 - mx), e4 = __expf(s4 - mx);
    float inv = 1.f / (e0 + e1 + e2 + e3 + e4);
    float v = e0 * bf2f(Vc[rb * ldq + off]) + e1 * bf2f(Vc[rs * ldq + off])
            + e2 * bf2f(Vc[ra * ldq + off]) + e3 * bf2f(Vh0[rs * ldh + off])
            + e4 * Vcen[rc + off];
    ctxb[rs * HH + off] = f2bf(v * inv);
  }
}

// ============ relu + layernorm over bf16 rows of 768 -> bf16
__global__ __launch_bounds__(256) void relu_ln_bf(
    const ushort_t* __restrict__ x, const float* __restrict__ w, const float* __restrict__ b,
    ushort_t* __restrict__ ybf)
{
  int row = blockIdx.x;
  const ushort_t* xr = x + (size_t)row * HH;
  float v[3];
  float sum = 0.f, sumsq = 0.f;
#pragma unroll
  for (int j = 0; j < 3; ++j) {
    float t = bf2f(xr[threadIdx.x + j * 256]);
    t = fmaxf(t, 0.f);
    v[j] = t;
    sum += t; sumsq += t * t;
  }
#pragma unroll
  for (int d = 1; d < 64; d <<= 1) { sum += __shfl_xor(sum, d); sumsq += __shfl_xor(sumsq, d); }
  __shared__ float ws_[4], wsq_[4];
  int wave = threadIdx.x >> 6, lane = threadIdx.x & 63;
  if (lane == 0) { ws_[wave] = sum; wsq_[wave] = sumsq; }
  __syncthreads();
  sum = ws_[0] + ws_[1] + ws_[2] + ws_[3];
  sumsq = wsq_[0] + wsq_[1] + wsq_[2] + wsq_[3];
  float mean = sum * (1.0f / HH);
  float var = sumsq * (1.0f / HH) - mean * mean;
  float rstd = rsqrtf(var + 1e-12f);
#pragma unroll
  for (int j = 0; j < 3; ++j) {
    int cidx = threadIdx.x + j * 256;
    float o = w[cidx] * (v[j] - mean) * rstd + b[cidx];
    ybf[(size_t)row * HH + cidx] = f2bf(o);
  }
}

// ============ relu + layernorm f32 (center rows)
__global__ __launch_bounds__(256) void relu_ln_f32(
    const float* __restrict__ x, const float* __restrict__ w, const float* __restrict__ b,
    float* __restrict__ y)
{
  int row = blockIdx.x;
  const float* xr = x + (size_t)row * HH;
  float v[3];
  float sum = 0.f, sumsq = 0.f;
#pragma unroll
  for (int j = 0; j < 3; ++j) {
    float t = fmaxf(xr[threadIdx.x + j * 256], 0.f);
    v[j] = t;
    sum += t; sumsq += t * t;
  }
#pragma unroll
  for (int d = 1; d < 64; d <<= 1) { sum += __shfl_xor(sum, d); sumsq += __shfl_xor(sumsq, d); }
  __shared__ float ws_[4], wsq_[4];
  int wave = threadIdx.x >> 6, lane = threadIdx.x & 63;
  if (lane == 0) { ws_[wave] = sum; wsq_[wave] = sumsq; }
  __syncthreads();
  sum = ws_[0] + ws_[1] + ws_[2] + ws_[3];
  sumsq = wsq_[0] + wsq_[1] + wsq_[2] + wsq_[3];
  float mean = sum * (1.0f / HH);
  float var = sumsq * (1.0f / HH) - mean * mean;
  float rstd = rsqrtf(var + 1e-12f);
#pragma unroll
  for (int j = 0; j < 3; ++j) {
    int cidx = threadIdx.x + j * 256;
    y[(size_t)row * HH + cidx] = w[cidx] * (v[j] - mean) * rstd + b[cidx];
  }
}

// ============ rel attention: Kr/Vr bf16 strided, Krc/Vrc f32
__global__ __launch_bounds__(256) void rel_attn(
    const float* __restrict__ Qr, const float* __restrict__ Krc, const ushort_t* __restrict__ Kr,
    const float* __restrict__ Vrc, const ushort_t* __restrict__ Vr, int ldkv,
    float* __restrict__ ctx)
{
  int b = blockIdx.x, h = blockIdx.y;
  __shared__ float qs[64];
  __shared__ float sc[513];
  __shared__ float part[4][64];
  __shared__ float redm[4], redsum[4];
  int t = threadIdx.x, lane = t & 63, wave = t >> 6;
  if (t < 64) qs[t] = Qr[b * HH + h * HDIM + t];
  __syncthreads();
  for (int j = t; j < 513; j += 256) {
    float acc = 0.f;
    if (j == 0) {
      const float* kp = Krc + b * HH + h * HDIM;
      for (int d = 0; d < HDIM; ++d) acc = fmaf(qs[d], kp[d], acc);
    } else {
      const ushort_t* kp = Kr + (size_t)(b * SS + j - 1) * ldkv + h * HDIM;
#pragma unroll 8
      for (int d = 0; d < HDIM; ++d) acc = fmaf(qs[d], bf2f(kp[d]), acc);
    }
    sc[j] = acc * 0.125f;
  }
  __syncthreads();
  float m = -1e30f;
  for (int j = t; j < 513; j += 256) m = fmaxf(m, sc[j]);
#pragma unroll
  for (int d = 1; d < 64; d <<= 1) m = fmaxf(m, __shfl_xor(m, d));
  if (lane == 0) redm[wave] = m;
  __syncthreads();
  m = fmaxf(fmaxf(redm[0], redm[1]), fmaxf(redm[2], redm[3]));
  float lsum = 0.f;
  for (int j = t; j < 513; j += 256) { float e = __expf(sc[j] - m); sc[j] = e; lsum += e; }
#pragma unroll
  for (int d = 1; d < 64; d <<= 1) lsum += __shfl_xor(lsum, d);
  if (lane == 0) redsum[wave] = lsum;
  __syncthreads();
  float total = redsum[0] + redsum[1] + redsum[2] + redsum[3];
  float accv = 0.f;
  for (int j = wave; j < 513; j += 4) {
    float vv = (j == 0) ? Vrc[b * HH + h * HDIM + lane]
                        : bf2f(Vr[(size_t)(b * SS + j - 1) * ldkv + h * HDIM + lane]);
    accv = fmaf(sc[j], vv, accv);
  }
  part[wave][lane] = accv;
  __syncthreads();
  if (wave == 0) {
    float r = (part[0][lane] + part[1][lane] + part[2][lane] + part[3][lane]) / total;
    ctx[b * HH + h * HDIM + lane] = r;
  }
}

// ============ merged tail + rope: blocks [0,384) tail, [384,896) rope
__global__ void tail_rope(const float* __restrict__ outputs,
                          const float* __restrict__ tw, const float* __restrict__ tb,
                          float* __restrict__ bias2,
                          float* __restrict__ qw, float* __restrict__ kw)
{
  int bid = blockIdx.x;
  if (bid < 384) {
    int idx = bid * 256 + threadIdx.x;
    int row = idx / 24, c = idx % 24;
    float acc = tb[c];
    const float* a = outputs + (size_t)row * 128;
#pragma unroll 16
    for (int k = 0; k < 128; ++k) acc = fmaf(a[k], tw[k * 24 + c], acc);
    bias2[idx] = acc * 0.5f;
  } else {
    int idx = (bid - 384) * 256 + threadIdx.x; // row*32 + i
    int row = idx >> 5;
    int i = idx & 31;
    int s = row & 511;
    float inv = powf(10000.0f, -2.0f * (float)i / 64.0f);
    float ang = (float)s * inv;
    float sn = sinf(ang), cn = cosf(ang);
    const float* o = outputs + (size_t)row * 128 + i * 4;
    float q0 = o[0], k0 = o[1], q1 = o[2], k1 = o[3];
    float* qp = qw + (size_t)row * 64 + i * 2;
    float* kp = kw + (size_t)row * 64 + i * 2;
    qp[0] = q0 * cn - q1 * sn; qp[1] = q1 * cn + q0 * sn;
    kp[0] = k0 * cn - k1 * sn; kp[1] = k1 * cn + k0 * sn;
  }
}

// ============ final logits
__global__ __launch_bounds__(256) void final_kernel(
    const float* __restrict__ qw, const float* __restrict__ kw,
    const float* __restrict__ bias2, const float* __restrict__ mask,
    float* __restrict__ out)
{
  int b = blockIdx.z;
  int mt = blockIdx.y * 32;
  int nt = blockIdx.x * 32;
  __shared__ float qs[32][68];
  __shared__ float ks[32][68];
  int t = threadIdx.x;
  {
    int idx = t * 8;
    int r = idx >> 6, c = idx & 63;
    const float* sq = qw + (size_t)(b * SS + mt + r) * 64 + c;
    const float* sk = kw + (size_t)(b * SS + nt + r) * 64 + c;
    *(float4*)&qs[r][c]     = *(const float4*)(sq);
    *(float4*)&qs[r][c + 4] = *(const float4*)(sq + 4);
    *(float4*)&ks[r][c]     = *(const float4*)(sk);
    *(float4*)&ks[r][c + 4] = *(const float4*)(sk + 4);
  }
  __syncthreads();
  int m = t >> 3;
  int n0 = (t & 7) * 4;
  float d0 = 0.f, d1 = 0.f, d2 = 0.f, d3 = 0.f;
#pragma unroll
  for (int d = 0; d < 64; d += 4) {
    float4 qv = *(const float4*)&qs[m][d];
    float4 k0 = *(const float4*)&ks[n0 + 0][d];
    float4 k1 = *(const float4*)&ks[n0 + 1][d];
    float4 k2 = *(const float4*)&ks[n0 + 2][d];
    float4 k3 = *(const float4*)&ks[n0 + 3][d];
    d0 += qv.x * k0.x + qv.y * k0.y + qv.z * k0.z + qv.w * k0.w;
    d1 += qv.x * k1.x + qv.y * k1.y + qv.z * k1.z + qv.w * k1.w;
    d2 += qv.x * k2.x + qv.y * k2.y + qv.z * k2.z + qv.w * k2.w;
    d3 += qv.x * k3.x + qv.y * k3.y + qv.z * k3.z + qv.w * k3.w;
  }
  int gm = mt + m;
  int gn = nt + n0;
  d0 *= 0.125f; d1 *= 0.125f; d2 *= 0.125f; d3 *= 0.125f;
  float mm = mask[b * SS + gm];
  float mn0 = mask[b * SS + gn + 0];
  float mn1 = mask[b * SS + gn + 1];
  float mn2 = mask[b * SS + gn + 2];
  float mn3 = mask[b * SS + gn + 3];
  const float* bmp  = bias2 + (size_t)(b * SS + gm) * 24;
  const float* bnp0 = bias2 + (size_t)(b * SS + gn + 0) * 24;
  const float* bnp1 = bias2 + (size_t)(b * SS + gn + 1) * 24;
  const float* bnp2 = bias2 + (size_t)(b * SS + gn + 2) * 24;
  const float* bnp3 = bias2 + (size_t)(b * SS + gn + 3) * 24;
#pragma unroll
  for (int h = 0; h < NLH; ++h) {
    float tb = bmp[2 * h + 1];
    float v0 = d0 + bnp0[2 * h] + tb;
    float v1 = d1 + bnp1[2 * h] + tb;
    float v2 = d2 + bnp2[2 * h] + tb;
    float v3 = d3 + bnp3[2 * h] + tb;
    v0 = v0 * mm + NEGV * (1.f - mm); v1 = v1 * mm + NEGV * (1.f - mm);
    v2 = v2 * mm + NEGV * (1.f - mm); v3 = v3 * mm + NEGV * (1.f - mm);
    v0 = v0 * mn0 + NEGV * (1.f - mn0); v1 = v1 * mn1 + NEGV * (1.f - mn1);
    v2 = v2 * mn2 + NEGV * (1.f - mn2); v3 = v3 * mn3 + NEGV * (1.f - mn3);
    if (gm > gn + 0) v0 -= 1000000000000.0f;
    if (gm > gn + 1) v1 -= 1000000000000.0f;
    if (gm > gn + 2) v2 -= 1000000000000.0f;
    if (gm > gn + 3) v3 -= 1000000000000.0f;
    float4 o = make_float4(v0, v1, v2, v3);
    *(float4*)(out + ((((size_t)(b * NLH + h)) * SS + gm) * SS + gn)) = o;
  }
}

extern "C" void kernel_launch(void* const* d_in, const int* in_sizes, int n_in,
                              void* d_out, int out_size, void* d_ws, size_t ws_size,
                              hipStream_t stream)
{
  const float* bert    = (const float*)d_in[0];
  const float* amask   = (const float*)d_in[1];
  const float* dense_w = (const float*)d_in[2];
  const float* dense_b = (const float*)d_in[3];
  const float* sat_qw  = (const float*)d_in[4];
  const float* sat_qb  = (const float*)d_in[5];
  const float* sat_kw  = (const float*)d_in[6];
  const float* sat_kb  = (const float*)d_in[7];
  const float* sat_vw  = (const float*)d_in[8];
  const float* sat_vb  = (const float*)d_in[9];
  const float* sat_ow  = (const float*)d_in[10];
  const float* sat_ob  = (const float*)d_in[11];
  const float* rel_qw  = (const float*)d_in[12];
  const float* rel_qb  = (const float*)d_in[13];
  const float* rel_kw  = (const float*)d_in[14];
  const float* rel_kb  = (const float*)d_in[15];
  const float* rel_vw  = (const float*)d_in[16];
  const float* rel_vb  = (const float*)d_in[17];
  const float* rel_ow  = (const float*)d_in[18];
  const float* rel_ob  = (const float*)d_in[19];
  const float* lns_w   = (const float*)d_in[20];
  const float* lns_b   = (const float*)d_in[21];
  const float* lnr_w   = (const float*)d_in[22];
  const float* lnr_b   = (const float*)d_in[23];
  const float* head_w  = (const float*)d_in[24];
  const float* head_b  = (const float*)d_in[25];
  const float* tail_w  = (const float*)d_in[26];
  const float* tail_b  = (const float*)d_in[27];

  float* out = (float*)d_out;
  char*  ws  = (char*)d_ws;

  // ---- ws carve-up ----
  size_t off = 0;
  auto alloc = [&](size_t bytes) { char* p = ws + off; off += (bytes + 255) & ~(size_t)255; return p; };
  ushort_t* bert_bf   = (ushort_t*)alloc((size_t)BSROWS * 448 * 2);
  ushort_t* Wt_dense  = (ushort_t*)alloc((size_t)768 * 448 * 2);
  ushort_t* Wt_satqkv = (ushort_t*)alloc((size_t)2304 * 768 * 2);
  ushort_t* Wt_satow  = (ushort_t*)alloc((size_t)768 * 768 * 2);
  ushort_t* Wt_relkv  = (ushort_t*)alloc((size_t)1536 * 768 * 2);
  ushort_t* Wt_head   = (ushort_t*)alloc((size_t)128 * 768 * 2);
  ushort_t* hidden0_bf= (ushort_t*)alloc((size_t)BSROWS * HH * 2);
  ushort_t* ctx_bf    = (ushort_t*)alloc((size_t)BSROWS * HH * 2);
  ushort_t* csA_bf    = (ushort_t*)alloc((size_t)BSROWS * HH * 2);
  float* b_satqkv = (float*)alloc(2304 * 4);
  float* b_relkv  = (float*)alloc(1536 * 4);
  float* center   = (float*)alloc(6144 * 4);
  float* center2  = (float*)alloc(6144 * 4);
  float* Kcen     = (float*)alloc(6144 * 4);
  float* Vcen     = (float*)alloc(6144 * 4);
  float* Qr       = (float*)alloc(6144 * 4);
  float* Krc      = (float*)alloc(6144 * 4);
  float* Vrc      = (float*)alloc(6144 * 4);
  float* ctxr     = (float*)alloc(6144 * 4);
  float* relo     = (float*)alloc(6144 * 4);
  float* outputs  = (float*)alloc((size_t)BSROWS * 128 * 4);
  float* bias2    = (float*)alloc((size_t)BSROWS * 24 * 4);
  float* qwbuf    = (float*)alloc((size_t)BSROWS * 64 * 4);
  float* kwbuf    = (float*)alloc((size_t)BSROWS * 64 * 4);

  // ---- d_out as bf16 scratch (fully overwritten by final_kernel) ----
  // QKV1_bf: [4096][2304] at base; region2 holds tmp1 -> KrVr -> QKV2 (sequential liveness)
  ushort_t* QKV1_bf = (ushort_t*)out;
  ushort_t* region2 = QKV1_bf + (size_t)BSROWS * 2304;
  ushort_t* tmp1_bf = region2;                 // [4096][768]
  ushort_t* KrVr_bf = region2;                 // [4096][1536]
  ushort_t* QKV2_bf = region2;                 // [4096][2304]
  ushort_t* tmp2_bf = QKV1_bf;                 // [4096][768], after QKV1 dead

  dim3 blk(256);

  // ---- prep ----
  {
    TJobs tj;
    tj.j[0] = { dense_w, Wt_dense,  432, 768, 448, 0 };
    tj.j[1] = { sat_qw,  Wt_satqkv, 768, 768, 768, 0 };
    tj.j[2] = { sat_kw,  Wt_satqkv, 768, 768, 768, 768 };
    tj.j[3] = { sat_vw,  Wt_satqkv, 768, 768, 768, 1536 };
    tj.j[4] = { sat_ow,  Wt_satow,  768, 768, 768, 0 };
    tj.j[5] = { rel_kw,  Wt_relkv,  768, 768, 768, 0 };
    tj.j[6] = { rel_vw,  Wt_relkv,  768, 768, 768, 768 };
    tj.j[7] = { head_w,  Wt_head,   768, 128, 768, 0 };
    transpose_weights<<<dim3(24, 24, 8), blk, 0, stream>>>(tj);
  }
  {
    int total = BSROWS * 448 + 2304 + 1536;
    prep_misc<<<(total + 255) / 256, blk, 0, stream>>>(
        bert, sat_qb, sat_kb, sat_vb, rel_kb, rel_vb, bert_bf, b_satqkv, b_relkv);
  }

  // ---- dense ----
  gemm_bf16<<<dim3(6, 32), blk, 0, stream>>>(bert_bf, 448, Wt_dense, 448, dense_b,
                                             nullptr, nullptr, hidden0_bf, HH, 448);
  mean_bf<<<dim3(6, 8), blk, 0, stream>>>(hidden0_bf, center);

  // ---- iter 1 ----
  gemm_bf16<<<dim3(18, 32), blk, 0, stream>>>(hidden0_bf, HH, Wt_satqkv, HH, b_satqkv,
                                              nullptr, nullptr, QKV1_bf, 2304, HH);
  {
    SmallJobs jobs;
    jobs.j[0] = { sat_kw, sat_kb, nullptr, Kcen };
    jobs.j[1] = { sat_vw, sat_vb, nullptr, Vcen };
    jobs.j[2] = { rel_qw, rel_qb, nullptr, Qr };
    jobs.j[3] = { rel_kw, rel_kb, nullptr, Krc };
    jobs.j[4] = { rel_vw, rel_vb, nullptr, Vrc };
    gemm_skinny<<<dim3(24, 5), blk, 0, stream>>>(center, jobs);
  }
  sat_attn<<<BSROWS, 256, 0, stream>>>(QKV1_bf, QKV1_bf + 768, QKV1_bf + 1536, 2304,
                                       QKV1_bf + 768, QKV1_bf + 1536, 2304,
                                       Kcen, Vcen, ctx_bf);
  gemm_bf16<<<dim3(6, 32), blk, 0, stream>>>(ctx_bf, HH, Wt_satow, HH, sat_ob,
                                             hidden0_bf, nullptr, tmp1_bf, HH, HH);
  relu_ln_bf<<<BSROWS, 256, 0, stream>>>(tmp1_bf, lns_w, lns_b, csA_bf);

  // rel branch (iter-2 center is dead, only iter-1 needed)
  gemm_bf16<<<dim3(12, 32), blk, 0, stream>>>(csA_bf, HH, Wt_relkv, HH, b_relkv,
                                              nullptr, nullptr, KrVr_bf, 1536, HH);
  rel_attn<<<dim3(8, 12), 256, 0, stream>>>(Qr, Krc, KrVr_bf, Vrc, KrVr_bf + 768, 1536, ctxr);
  {
    SmallJobs jobs;
    jobs.j[0] = { rel_ow, rel_ob, center, relo };
    gemm_skinny<<<dim3(24, 1), blk, 0, stream>>>(ctxr, jobs);
  }
  relu_ln_f32<<<8, 256, 0, stream>>>(relo, lnr_w, lnr_b, center2);

  // ---- iter 2 ----
  gemm_bf16<<<dim3(18, 32), blk, 0, stream>>>(csA_bf, HH, Wt_satqkv, HH, b_satqkv,
                                              nullptr, nullptr, QKV2_bf, 2304, HH);
  {
    SmallJobs jobs;
    jobs.j[0] = { sat_kw, sat_kb, nullptr, Kcen };
    jobs.j[1] = { sat_vw, sat_vb, nullptr, Vcen };
    gemm_skinny<<<dim3(24, 2), blk, 0, stream>>>(center2, jobs);
  }
  sat_attn<<<BSROWS, 256, 0, stream>>>(QKV2_bf, QKV2_bf + 768, QKV2_bf + 1536, 2304,
                                       QKV1_bf + 768, QKV1_bf + 1536, 2304,
                                       Kcen, Vcen, ctx_bf);
  gemm_bf16<<<dim3(6, 32), blk, 0, stream>>>(ctx_bf, HH, Wt_satow, HH, sat_ob,
                                             csA_bf, nullptr, tmp2_bf, HH, HH);
  relu_ln_bf<<<BSROWS, 256, 0, stream>>>(tmp2_bf, lns_w, lns_b, csA_bf);

  // ---- head / rope+tail / logits ----
  gemm_bf16<<<dim3(1, 32), blk, 0, stream>>>(csA_bf, HH, Wt_head, HH, head_b,
                                             nullptr, outputs, nullptr, 128, HH);
  tail_rope<<<896, 256, 0, stream>>>(outputs, tail_w, tail_b, bias2, qwbuf, kwbuf);
  final_kernel<<<dim3(16, 16, 8), 256, 0, stream>>>(qwbuf, kwbuf, bias2, amask, out);
}

// Round 5
// 337.530 us; speedup vs baseline: 7.2397x; 1.0563x over previous
//
#include <hip/hip_runtime.h>
#include <cstdint>
#include <cstddef>

#define HH 768
#define SS 512
#define NBATCH 8
#define NLH 12
#define HDIM 64
#define BSROWS 4096
static constexpr float NEGV = -1000000000000.0f;

typedef unsigned short ushort_t;
typedef __attribute__((ext_vector_type(4))) float fx4;
typedef __attribute__((ext_vector_type(8))) short sx8;

__device__ __forceinline__ ushort_t f2bf(float f) {
  uint32_t u = __float_as_uint(f);
  uint32_t r = (u + 0x7FFFu + ((u >> 16) & 1u)) >> 16;
  return (ushort_t)r;
}
__device__ __forceinline__ float bf2f(ushort_t h) {
  return __uint_as_float(((uint32_t)h) << 16);
}

__device__ __forceinline__ void async_copy16(void* lds, const void* g) {
  __builtin_amdgcn_global_load_lds(
      (const __attribute__((address_space(1))) void*)g,
      (__attribute__((address_space(3))) void*)lds, 16, 0, 0);
}

// ============ bf16 MFMA GEMM: 128x128 tile, BK=64, 4 waves, split-output epilogue.
// dst = (bn >= nsplit) ? Cb2 : Cb.  bias indexed by global col. resb only with Cb path.
__global__ __launch_bounds__(256) void gemm_bf16(
    const ushort_t* __restrict__ A, int lda,
    const ushort_t* __restrict__ B, int ldb,
    const float* __restrict__ bias,
    const ushort_t* __restrict__ resb,
    ushort_t* __restrict__ Cb, int ldo,
    ushort_t* __restrict__ Cb2, int ldo2, int nsplit, int K)
{
  __shared__ ushort_t As[128 * 64];
  __shared__ ushort_t Bs[128 * 64];
  const int tid = threadIdx.x;
  const int bm = blockIdx.y * 128;
  const int bn = blockIdx.x * 128;
  const int l = tid & 63;
  const int w = tid >> 6;
  const int wr = w >> 1, wc = w & 1;
  const int r8 = tid >> 3;
  const int sl = tid & 7;

  fx4 acc[4][4];
#pragma unroll
  for (int m = 0; m < 4; ++m)
#pragma unroll
    for (int n = 0; n < 4; ++n) acc[m][n] = (fx4)0.f;

  for (int k0 = 0; k0 < K; k0 += 64) {
#pragma unroll
    for (int i = 0; i < 4; ++i) {
      int row = i * 32 + r8;
      int srcs = sl ^ (row & 7);
      async_copy16((char*)As + i * 4096 + tid * 16,
                   A + (size_t)(bm + row) * lda + k0 + srcs * 8);
    }
#pragma unroll
    for (int i = 0; i < 4; ++i) {
      int row = i * 32 + r8;
      int srcs = sl ^ (row & 7);
      async_copy16((char*)Bs + i * 4096 + tid * 16,
                   B + (size_t)(bn + row) * ldb + k0 + srcs * 8);
    }
    __syncthreads();
#pragma unroll
    for (int kk = 0; kk < 2; ++kk) {
      sx8 av[4], bv[4];
      const int so = (l >> 4) + kk * 4;
#pragma unroll
      for (int m = 0; m < 4; ++m) {
        int r = wr * 64 + m * 16 + (l & 15);
        av[m] = *(const sx8*)((const char*)As + r * 128 + ((so ^ (r & 7)) * 16));
      }
#pragma unroll
      for (int n = 0; n < 4; ++n) {
        int r = wc * 64 + n * 16 + (l & 15);
        bv[n] = *(const sx8*)((const char*)Bs + r * 128 + ((so ^ (r & 7)) * 16));
      }
#pragma unroll
      for (int m = 0; m < 4; ++m)
#pragma unroll
        for (int n = 0; n < 4; ++n)
          acc[m][n] = __builtin_amdgcn_mfma_f32_16x16x32_bf16(av[m], bv[n], acc[m][n], 0, 0, 0);
    }
    __syncthreads();
  }

  const bool second = (bn >= nsplit);
  ushort_t* dst = second ? Cb2 : Cb;
  const int ld = second ? ldo2 : ldo;
  const int csub = second ? nsplit : 0;
  const int cr0 = bm + wr * 64 + (l >> 4) * 4;
  const int cc0 = bn + wc * 64 + (l & 15);
#pragma unroll
  for (int m = 0; m < 4; ++m) {
#pragma unroll
    for (int n = 0; n < 4; ++n) {
      int col = cc0 + n * 16;
      float bcol = bias[col];
#pragma unroll
      for (int j = 0; j < 4; ++j) {
        int row = cr0 + m * 16 + j;
        size_t off = (size_t)row * ld + (col - csub);
        float v = acc[m][n][j] + bcol;
        if (resb) v += bf2f(resb[off]);
        dst[off] = f2bf(v);
      }
    }
  }
}

// ============ fused head GEMM (M-tile 128, N=128 full) + RoPE + tail-bias epilogue
__global__ __launch_bounds__(256) void head_fused(
    const ushort_t* __restrict__ A,       // csA bf16 [4096][768]
    const ushort_t* __restrict__ B,       // Wt_head bf16 [128][768]
    const float* __restrict__ head_b,
    const float* __restrict__ tail_w,     // [128][24]
    const float* __restrict__ tail_b,     // [24]
    float* __restrict__ qw, float* __restrict__ kw,   // [4096][64]
    float* __restrict__ bias2)            // [4096][24]
{
  __shared__ ushort_t As[128 * 64];
  __shared__ ushort_t Bs[128 * 64];
  __shared__ float tile[128][130];
  const int tid = threadIdx.x;
  const int bm = blockIdx.x * 128;
  const int l = tid & 63;
  const int w = tid >> 6;
  const int wr = w >> 1, wc = w & 1;
  const int r8 = tid >> 3;
  const int sl = tid & 7;

  fx4 acc[4][4];
#pragma unroll
  for (int m = 0; m < 4; ++m)
#pragma unroll
    for (int n = 0; n < 4; ++n) acc[m][n] = (fx4)0.f;

  for (int k0 = 0; k0 < HH; k0 += 64) {
#pragma unroll
    for (int i = 0; i < 4; ++i) {
      int row = i * 32 + r8;
      int srcs = sl ^ (row & 7);
      async_copy16((char*)As + i * 4096 + tid * 16,
                   A + (size_t)(bm + row) * HH + k0 + srcs * 8);
    }
#pragma unroll
    for (int i = 0; i < 4; ++i) {
      int row = i * 32 + r8;
      int srcs = sl ^ (row & 7);
      async_copy16((char*)Bs + i * 4096 + tid * 16,
                   B + (size_t)row * HH + k0 + srcs * 8);
    }
    __syncthreads();
#pragma unroll
    for (int kk = 0; kk < 2; ++kk) {
      sx8 av[4], bv[4];
      const int so = (l >> 4) + kk * 4;
#pragma unroll
      for (int m = 0; m < 4; ++m) {
        int r = wr * 64 + m * 16 + (l & 15);
        av[m] = *(const sx8*)((const char*)As + r * 128 + ((so ^ (r & 7)) * 16));
      }
#pragma unroll
      for (int n = 0; n < 4; ++n) {
        int r = wc * 64 + n * 16 + (l & 15);
        bv[n] = *(const sx8*)((const char*)Bs + r * 128 + ((so ^ (r & 7)) * 16));
      }
#pragma unroll
      for (int m = 0; m < 4; ++m)
#pragma unroll
        for (int n = 0; n < 4; ++n)
          acc[m][n] = __builtin_amdgcn_mfma_f32_16x16x32_bf16(av[m], bv[n], acc[m][n], 0, 0, 0);
    }
    __syncthreads();
  }

  const int cr0 = wr * 64 + (l >> 4) * 4;
  const int cc0 = wc * 64 + (l & 15);
#pragma unroll
  for (int m = 0; m < 4; ++m)
#pragma unroll
    for (int n = 0; n < 4; ++n) {
      int col = cc0 + n * 16;
      float bcol = head_b[col];
#pragma unroll
      for (int j = 0; j < 4; ++j)
        tile[cr0 + m * 16 + j][col] = acc[m][n][j] + bcol;
    }
  __syncthreads();

  // RoPE: 128 rows x 32 pairs
  for (int t = tid; t < 128 * 32; t += 256) {
    int r = t >> 5, i = t & 31;
    int s = (bm + r) & 511;
    float inv = powf(10000.0f, -(float)i / 32.0f);
    float ang = (float)s * inv;
    float sn = sinf(ang), cn = cosf(ang);
    float q0 = tile[r][4 * i + 0], k0 = tile[r][4 * i + 1];
    float q1 = tile[r][4 * i + 2], k1 = tile[r][4 * i + 3];
    float* qp = qw + (size_t)(bm + r) * 64 + i * 2;
    float* kp = kw + (size_t)(bm + r) * 64 + i * 2;
    qp[0] = q0 * cn - q1 * sn; qp[1] = q1 * cn + q0 * sn;
    kp[0] = k0 * cn - k1 * sn; kp[1] = k1 * cn + k0 * sn;
  }
  // tail: 128 rows x 24 cols
  for (int t = tid; t < 128 * 24; t += 256) {
    int r = t / 24, c = t % 24;
    float acc2 = tail_b[c];
#pragma unroll 16
    for (int k = 0; k < 128; ++k) acc2 = fmaf(tile[r][k], tail_w[k * 24 + c], acc2);
    bias2[(size_t)(bm + r) * 24 + c] = acc2 * 0.5f;
  }
}

// ============ combined prep: z<8 weight transposes, z==8 bert->bf16 + bias concat
struct TJob { const float* src; ushort_t* dst; int K, N, Kpad, rowOff; };
struct PrepArgs {
  TJob j[8];
  const float* bert; ushort_t* bert_bf;
  const float* rkb; const float* rvb; const float* sqb; const float* skb; const float* svb;
  float* b_merged;   // [3840] = relk|relv|satq|satk|satv
};
__global__ __launch_bounds__(256) void prep_all(PrepArgs pa)
{
  if (blockIdx.z < 8) {
    TJob jb = pa.j[blockIdx.z];
    int k0 = blockIdx.x * 32, n0 = blockIdx.y * 32;
    if (k0 >= jb.Kpad || n0 >= jb.N) return;
    __shared__ float t[32][33];
    int tx = threadIdx.x & 31, ty = threadIdx.x >> 5;
#pragma unroll
    for (int i = 0; i < 4; ++i) {
      int k = k0 + ty + i * 8;
      float v = 0.f;
      if (k < jb.K && n0 + tx < jb.N) v = jb.src[(size_t)k * jb.N + n0 + tx];
      t[ty + i * 8][tx] = v;
    }
    __syncthreads();
#pragma unroll
    for (int i = 0; i < 4; ++i) {
      int n = n0 + ty + i * 8;
      int k = k0 + tx;
      if (n < jb.N && k < jb.Kpad)
        jb.dst[(size_t)(jb.rowOff + n) * jb.Kpad + k] = f2bf(t[tx][ty + i * 8]);
    }
  } else {
    const int NB = BSROWS * 448;
    const int total = NB + 3840;
    int start = (blockIdx.y * 24 + blockIdx.x) * 256 + threadIdx.x;
    for (int i = start; i < total; i += 24 * 24 * 256) {
      if (i < NB) {
        int r = i / 448, c = i % 448;
        pa.bert_bf[i] = (c < 432) ? f2bf(pa.bert[(size_t)r * 432 + c]) : (ushort_t)0;
      } else {
        int c = i - NB;
        float v;
        if (c < 768) v = pa.rkb[c];
        else if (c < 1536) v = pa.rvb[c - 768];
        else if (c < 2304) v = pa.sqb[c - 1536];
        else if (c < 3072) v = pa.skb[c - 2304];
        else v = pa.svb[c - 3072];
        pa.b_merged[c] = v;
      }
    }
  }
}

// ============ center = mean over s (bf16 input), grid (6,8)
__global__ __launch_bounds__(256) void mean_bf(const ushort_t* __restrict__ h0,
                                               float* __restrict__ center)
{
  int b = blockIdx.y;
  int col = blockIdx.x * 128 + (threadIdx.x & 127);
  int half = threadIdx.x >> 7;
  const ushort_t* p = h0 + ((size_t)b * SS + half * 256) * HH + col;
  float s = 0.f;
#pragma unroll 8
  for (int i = 0; i < 256; ++i) s += bf2f(p[(size_t)i * HH]);
  __shared__ float red[2][128];
  red[half][threadIdx.x & 127] = s;
  __syncthreads();
  if (half == 0)
    center[b * HH + col] = (red[0][threadIdx.x] + red[1][threadIdx.x]) * (1.0f / 512.0f);
}

// ============ skinny GEMM: M=8, K=768, N=768 (f32 weights), multi-job
struct SmallJob { const float* W; const float* bias; const float* res; float* C; };
struct SmallJobs { SmallJob j[5]; };
__global__ __launch_bounds__(256) void gemm_skinny(
    const float* __restrict__ A, SmallJobs jobs)
{
  __shared__ float As[8 * HH];
  __shared__ float part[8 * 8 * 32];
  const int tid = threadIdx.x;
  const SmallJob job = jobs.j[blockIdx.y];
#pragma unroll
  for (int i = 0; i < 6; ++i) {
    int idx = tid * 4 + i * 1024;
    *(float4*)&As[idx] = *(const float4*)(A + idx);
  }
  __syncthreads();
  const int c = tid & 31;
  const int col = (blockIdx.x << 5) + c;
  const int ks = tid >> 5;
  const float* Wp = job.W + (size_t)(ks * 96) * HH + col;
  float acc[8] = {};
#pragma unroll 8
  for (int k = 0; k < 96; ++k) {
    float wv = Wp[(size_t)k * HH];
    const float* ap = &As[ks * 96 + k];
#pragma unroll
    for (int m = 0; m < 8; ++m)
      acc[m] = fmaf(ap[m * HH], wv, acc[m]);
  }
#pragma unroll
  for (int m = 0; m < 8; ++m)
    part[ks * 256 + m * 32 + c] = acc[m];
  __syncthreads();
  const int m = tid >> 5;
  const int c2 = tid & 31;
  float s = 0.f;
#pragma unroll
  for (int k = 0; k < 8; ++k) s += part[k * 256 + m * 32 + c2];
  const int outcol = (blockIdx.x << 5) + c2;
  float v = s + job.bias[outcol];
  if (job.res) v += job.res[(size_t)m * HH + outcol];
  job.C[(size_t)m * HH + outcol] = v;
}

// ============ skinny with in-block relu+LN of staged A (A = relo f32 [8][768])
struct SmallJobs2 { SmallJob j[2]; };
__global__ __launch_bounds__(256) void skinny_ln(
    const float* __restrict__ relo, const float* __restrict__ lw, const float* __restrict__ lb,
    SmallJobs2 jobs)
{
  __shared__ float As[8 * HH];
  __shared__ float part[8 * 8 * 32];
  const int tid = threadIdx.x;
  const SmallJob job = jobs.j[blockIdx.y];
#pragma unroll
  for (int i = 0; i < 6; ++i) {
    int idx = tid * 4 + i * 1024;
    *(float4*)&As[idx] = *(const float4*)(relo + idx);
  }
  __syncthreads();
  // per-row relu+LN: row = tid>>5, 32 threads per row x 24 cols each
  {
    const int row = tid >> 5, lc = tid & 31;
    float s = 0.f, sq = 0.f;
#pragma unroll
    for (int e = 0; e < 24; ++e) {
      float x = fmaxf(As[row * HH + lc * 24 + e], 0.f);
      s += x; sq += x * x;
    }
#pragma unroll
    for (int d = 1; d < 32; d <<= 1) { s += __shfl_xor(s, d); sq += __shfl_xor(sq, d); }
    float mean = s * (1.0f / HH);
    float var = sq * (1.0f / HH) - mean * mean;
    float rstd = rsqrtf(var + 1e-12f);
#pragma unroll
    for (int e = 0; e < 24; ++e) {
      int cc = lc * 24 + e;
      float x = fmaxf(As[row * HH + cc], 0.f);
      As[row * HH + cc] = lw[cc] * (x - mean) * rstd + lb[cc];
    }
  }
  __syncthreads();
  const int c = tid & 31;
  const int col = (blockIdx.x << 5) + c;
  const int ks = tid >> 5;
  const float* Wp = job.W + (size_t)(ks * 96) * HH + col;
  float acc[8] = {};
#pragma unroll 8
  for (int k = 0; k < 96; ++k) {
    float wv = Wp[(size_t)k * HH];
    const float* ap = &As[ks * 96 + k];
#pragma unroll
    for (int m = 0; m < 8; ++m)
      acc[m] = fmaf(ap[m * HH], wv, acc[m]);
  }
#pragma unroll
  for (int m = 0; m < 8; ++m)
    part[ks * 256 + m * 32 + c] = acc[m];
  __syncthreads();
  const int m = tid >> 5;
  const int c2 = tid & 31;
  float s2 = 0.f;
#pragma unroll
  for (int k = 0; k < 8; ++k) s2 += part[k * 256 + m * 32 + c2];
  const int outcol = (blockIdx.x << 5) + c2;
  job.C[(size_t)m * HH + outcol] = s2 + job.bias[outcol];
}

// ============ star attention (bf16 QKV strided), bf16 ctx out
__global__ __launch_bounds__(256) void sat_attn(
    const ushort_t* __restrict__ Qc, const ushort_t* __restrict__ Kc,
    const ushort_t* __restrict__ Vc, int ldq,
    const ushort_t* __restrict__ Kh0, const ushort_t* __restrict__ Vh0, int ldh,
    const float* __restrict__ Kcen, const float* __restrict__ Vcen,
    ushort_t* __restrict__ ctxb)
{
  int i = blockIdx.x;
  int b = i >> 9, s = i & 511;
  int lane = threadIdx.x & 63;
  int wave = threadIdx.x >> 6;
  size_t rb = (size_t)(b * SS + ((s + 1) & 511));
  size_t rs = (size_t)i;
  size_t ra = (size_t)(b * SS + (s == 0 ? (SS - 1) : 0));
  size_t rc = (size_t)b * HH;
  for (int h = wave; h < NLH; h += 4) {
    int off = h * HDIM + lane;
    float q = bf2f(Qc[rs * ldq + off]);
    float s0 = q * bf2f(Kc[rb * ldq + off]);
    float s1 = q * bf2f(Kc[rs * ldq + off]);
    float s2 = q * bf2f(Kc[ra * ldq + off]);
    float s3 = q * bf2f(Kh0[rs * ldh + off]);
    float s4 = q * Kcen[rc + off];
#pragma unroll
    for (int d = 1; d < 64; d <<= 1) {
      s0 += __shfl_xor(s0, d); s1 += __shfl_xor(s1, d); s2 += __shfl_xor(s2, d);
      s3 += __shfl_xor(s3, d); s4 += __shfl_xor(s4, d);
    }
    const float sc = 0.125f;
    s0 *= sc; s1 *= sc; s2 *= sc; s3 *= sc; s4 *= sc;
    float mx = fmaxf(fmaxf(fmaxf(s0, s1), fmaxf(s2, s3)), s4);
    float e0 = __expf(s0 - mx), e1 = __expf(s1 - mx), e2 = __expf(s2 - mx);
    float e3 = __expf(s3 - mx), e4 = __expf(s4 - mx);
    float inv = 1.f / (e0 + e1 + e2 + e3 + e4);
    float v = e0 * bf2f(Vc[rb * ldq + off]) + e1 * bf2f(Vc[rs * ldq + off])
            + e2 * bf2f(Vc[ra * ldq + off]) + e3 * bf2f(Vh0[rs * ldh + off])
            + e4 * Vcen[rc + off];
    ctxb[rs * HH + off] = f2bf(v * inv);
  }
}

// ============ relu + layernorm over bf16 rows -> bf16
__global__ __launch_bounds__(256) void relu_ln_bf(
    const ushort_t* __restrict__ x, const float* __restrict__ w, const float* __restrict__ b,
    ushort_t* __restrict__ ybf)
{
  int row = blockIdx.x;
  const ushort_t* xr = x + (size_t)row * HH;
  float v[3];
  float sum = 0.f, sumsq = 0.f;
#pragma unroll
  for (int j = 0; j < 3; ++j) {
    float t = bf2f(xr[threadIdx.x + j * 256]);
    t = fmaxf(t, 0.f);
    v[j] = t;
    sum += t; sumsq += t * t;
  }
#pragma unroll
  for (int d = 1; d < 64; d <<= 1) { sum += __shfl_xor(sum, d); sumsq += __shfl_xor(sumsq, d); }
  __shared__ float ws_[4], wsq_[4];
  int wave = threadIdx.x >> 6, lane = threadIdx.x & 63;
  if (lane == 0) { ws_[wave] = sum; wsq_[wave] = sumsq; }
  __syncthreads();
  sum = ws_[0] + ws_[1] + ws_[2] + ws_[3];
  sumsq = wsq_[0] + wsq_[1] + wsq_[2] + wsq_[3];
  float mean = sum * (1.0f / HH);
  float var = sumsq * (1.0f / HH) - mean * mean;
  float rstd = rsqrtf(var + 1e-12f);
#pragma unroll
  for (int j = 0; j < 3; ++j) {
    int cidx = threadIdx.x + j * 256;
    float o = w[cidx] * (v[j] - mean) * rstd + b[cidx];
    ybf[(size_t)row * HH + cidx] = f2bf(o);
  }
}

// ============ rel attention: Kr/Vr bf16 strided, vectorized K-dot
__global__ __launch_bounds__(256) void rel_attn(
    const float* __restrict__ Qr, const float* __restrict__ Krc, const ushort_t* __restrict__ Kr,
    const float* __restrict__ Vrc, const ushort_t* __restrict__ Vr, int ldkv,
    float* __restrict__ ctx)
{
  int b = blockIdx.x, h = blockIdx.y;
  __shared__ float qs[64];
  __shared__ float sc[513];
  __shared__ float part[4][64];
  __shared__ float redm[4], redsum[4];
  int t = threadIdx.x, lane = t & 63, wave = t >> 6;
  if (t < 64) qs[t] = Qr[b * HH + h * HDIM + t];
  __syncthreads();
  for (int j = t; j < 513; j += 256) {
    float acc = 0.f;
    if (j == 0) {
      const float* kp = Krc + b * HH + h * HDIM;
#pragma unroll
      for (int d = 0; d < HDIM; ++d) acc = fmaf(qs[d], kp[d], acc);
    } else {
      const sx8* kv = (const sx8*)(Kr + (size_t)(b * SS + j - 1) * ldkv + h * HDIM);
#pragma unroll
      for (int dq = 0; dq < 8; ++dq) {
        sx8 v = kv[dq];
#pragma unroll
        for (int e = 0; e < 8; ++e)
          acc = fmaf(qs[dq * 8 + e], bf2f((ushort_t)v[e]), acc);
      }
    }
    sc[j] = acc * 0.125f;
  }
  __syncthreads();
  float m = -1e30f;
  for (int j = t; j < 513; j += 256) m = fmaxf(m, sc[j]);
#pragma unroll
  for (int d = 1; d < 64; d <<= 1) m = fmaxf(m, __shfl_xor(m, d));
  if (lane == 0) redm[wave] = m;
  __syncthreads();
  m = fmaxf(fmaxf(redm[0], redm[1]), fmaxf(redm[2], redm[3]));
  float lsum = 0.f;
  for (int j = t; j < 513; j += 256) { float e = __expf(sc[j] - m); sc[j] = e; lsum += e; }
#pragma unroll
  for (int d = 1; d < 64; d <<= 1) lsum += __shfl_xor(lsum, d);
  if (lane == 0) redsum[wave] = lsum;
  __syncthreads();
  float total = redsum[0] + redsum[1] + redsum[2] + redsum[3];
  float accv = 0.f;
#pragma unroll 8
  for (int j = wave; j < 513; j += 4) {
    float vv = (j == 0) ? Vrc[b * HH + h * HDIM + lane]
                        : bf2f(Vr[(size_t)(b * SS + j - 1) * ldkv + h * HDIM + lane]);
    accv = fmaf(sc[j], vv, accv);
  }
  part[wave][lane] = accv;
  __syncthreads();
  if (wave == 0) {
    float r = (part[0][lane] + part[1][lane] + part[2][lane] + part[3][lane]) / total;
    ctx[b * HH + h * HDIM + lane] = r;
  }
}

// ============ final logits
__global__ __launch_bounds__(256) void final_kernel(
    const float* __restrict__ qw, const float* __restrict__ kw,
    const float* __restrict__ bias2, const float* __restrict__ mask,
    float* __restrict__ out)
{
  int b = blockIdx.z;
  int mt = blockIdx.y * 32;
  int nt = blockIdx.x * 32;
  __shared__ float qs[32][68];
  __shared__ float ks[32][68];
  int t = threadIdx.x;
  {
    int idx = t * 8;
    int r = idx >> 6, c = idx & 63;
    const float* sq = qw + (size_t)(b * SS + mt + r) * 64 + c;
    const float* sk = kw + (size_t)(b * SS + nt + r) * 64 + c;
    *(float4*)&qs[r][c]     = *(const float4*)(sq);
    *(float4*)&qs[r][c + 4] = *(const float4*)(sq + 4);
    *(float4*)&ks[r][c]     = *(const float4*)(sk);
    *(float4*)&ks[r][c + 4] = *(const float4*)(sk + 4);
  }
  __syncthreads();
  int m = t >> 3;
  int n0 = (t & 7) * 4;
  float d0 = 0.f, d1 = 0.f, d2 = 0.f, d3 = 0.f;
#pragma unroll
  for (int d = 0; d < 64; d += 4) {
    float4 qv = *(const float4*)&qs[m][d];
    float4 k0 = *(const float4*)&ks[n0 + 0][d];
    float4 k1 = *(const float4*)&ks[n0 + 1][d];
    float4 k2 = *(const float4*)&ks[n0 + 2][d];
    float4 k3 = *(const float4*)&ks[n0 + 3][d];
    d0 += qv.x * k0.x + qv.y * k0.y + qv.z * k0.z + qv.w * k0.w;
    d1 += qv.x * k1.x + qv.y * k1.y + qv.z * k1.z + qv.w * k1.w;
    d2 += qv.x * k2.x + qv.y * k2.y + qv.z * k2.z + qv.w * k2.w;
    d3 += qv.x * k3.x + qv.y * k3.y + qv.z * k3.z + qv.w * k3.w;
  }
  int gm = mt + m;
  int gn = nt + n0;
  d0 *= 0.125f; d1 *= 0.125f; d2 *= 0.125f; d3 *= 0.125f;
  float mm = mask[b * SS + gm];
  float mn0 = mask[b * SS + gn + 0];
  float mn1 = mask[b * SS + gn + 1];
  float mn2 = mask[b * SS + gn + 2];
  float mn3 = mask[b * SS + gn + 3];
  const float* bmp  = bias2 + (size_t)(b * SS + gm) * 24;
  const float* bnp0 = bias2 + (size_t)(b * SS + gn + 0) * 24;
  const float* bnp1 = bias2 + (size_t)(b * SS + gn + 1) * 24;
  const float* bnp2 = bias2 + (size_t)(b * SS + gn + 2) * 24;
  const float* bnp3 = bias2 + (size_t)(b * SS + gn + 3) * 24;
#pragma unroll
  for (int h = 0; h < NLH; ++h) {
    float tb = bmp[2 * h + 1];
    float v0 = d0 + bnp0[2 * h] + tb;
    float v1 = d1 + bnp1[2 * h] + tb;
    float v2 = d2 + bnp2[2 * h] + tb;
    float v3 = d3 + bnp3[2 * h] + tb;
    v0 = v0 * mm + NEGV * (1.f - mm); v1 = v1 * mm + NEGV * (1.f - mm);
    v2 = v2 * mm + NEGV * (1.f - mm); v3 = v3 * mm + NEGV * (1.f - mm);
    v0 = v0 * mn0 + NEGV * (1.f - mn0); v1 = v1 * mn1 + NEGV * (1.f - mn1);
    v2 = v2 * mn2 + NEGV * (1.f - mn2); v3 = v3 * mn3 + NEGV * (1.f - mn3);
    if (gm > gn + 0) v0 -= 1000000000000.0f;
    if (gm > gn + 1) v1 -= 1000000000000.0f;
    if (gm > gn + 2) v2 -= 1000000000000.0f;
    if (gm > gn + 3) v3 -= 1000000000000.0f;
    float4 o = make_float4(v0, v1, v2, v3);
    *(float4*)(out + ((((size_t)(b * NLH + h)) * SS + gm) * SS + gn)) = o;
  }
}

extern "C" void kernel_launch(void* const* d_in, const int* in_sizes, int n_in,
                              void* d_out, int out_size, void* d_ws, size_t ws_size,
                              hipStream_t stream)
{
  const float* bert    = (const float*)d_in[0];
  const float* amask   = (const float*)d_in[1];
  const float* dense_w = (const float*)d_in[2];
  const float* dense_b = (const float*)d_in[3];
  const float* sat_qw  = (const float*)d_in[4];
  const float* sat_qb  = (const float*)d_in[5];
  const float* sat_kw  = (const float*)d_in[6];
  const float* sat_kb  = (const float*)d_in[7];
  const float* sat_vw  = (const float*)d_in[8];
  const float* sat_vb  = (const float*)d_in[9];
  const float* sat_ow  = (const float*)d_in[10];
  const float* sat_ob  = (const float*)d_in[11];
  const float* rel_qw  = (const float*)d_in[12];
  const float* rel_qb  = (const float*)d_in[13];
  const float* rel_kw  = (const float*)d_in[14];
  const float* rel_kb  = (const float*)d_in[15];
  const float* rel_vw  = (const float*)d_in[16];
  const float* rel_vb  = (const float*)d_in[17];
  const float* rel_ow  = (const float*)d_in[18];
  const float* rel_ob  = (const float*)d_in[19];
  const float* lns_w   = (const float*)d_in[20];
  const float* lns_b   = (const float*)d_in[21];
  const float* lnr_w   = (const float*)d_in[22];
  const float* lnr_b   = (const float*)d_in[23];
  const float* head_w  = (const float*)d_in[24];
  const float* head_b  = (const float*)d_in[25];
  const float* tail_w  = (const float*)d_in[26];
  const float* tail_b  = (const float*)d_in[27];

  float* out = (float*)d_out;
  char*  ws  = (char*)d_ws;

  // ---- ws carve-up ----
  size_t off = 0;
  auto alloc = [&](size_t bytes) { char* p = ws + off; off += (bytes + 255) & ~(size_t)255; return p; };
  ushort_t* bert_bf   = (ushort_t*)alloc((size_t)BSROWS * 448 * 2);
  ushort_t* Wt_dense  = (ushort_t*)alloc((size_t)768 * 448 * 2);
  ushort_t* Wt_big    = (ushort_t*)alloc((size_t)3840 * 768 * 2);  // relk|relv|satq|satk|satv
  ushort_t* Wt_satow  = (ushort_t*)alloc((size_t)768 * 768 * 2);
  ushort_t* Wt_head   = (ushort_t*)alloc((size_t)128 * 768 * 2);
  ushort_t* hidden0_bf= (ushort_t*)alloc((size_t)BSROWS * HH * 2);
  ushort_t* ctx_bf    = (ushort_t*)alloc((size_t)BSROWS * HH * 2);
  ushort_t* csA_bf    = (ushort_t*)alloc((size_t)BSROWS * HH * 2);
  float* b_merged = (float*)alloc(3840 * 4);
  float* center   = (float*)alloc(6144 * 4);
  float* Kcen     = (float*)alloc(6144 * 4);
  float* Vcen     = (float*)alloc(6144 * 4);
  float* Qr       = (float*)alloc(6144 * 4);
  float* Krc      = (float*)alloc(6144 * 4);
  float* Vrc      = (float*)alloc(6144 * 4);
  float* ctxr     = (float*)alloc(6144 * 4);
  float* relo     = (float*)alloc(6144 * 4);
  float* bias2    = (float*)alloc((size_t)BSROWS * 24 * 4);
  float* qwbuf    = (float*)alloc((size_t)BSROWS * 64 * 4);
  float* kwbuf    = (float*)alloc((size_t)BSROWS * 64 * 4);

  // ---- d_out as bf16 scratch (final_kernel overwrites everything) ----
  ushort_t* QKV1_bf = (ushort_t*)out;                                // [4096][2304]
  ushort_t* tmp1_bf = QKV1_bf + (size_t)BSROWS * 2304;               // [4096][768]
  ushort_t* KrVr_bf = tmp1_bf + (size_t)BSROWS * 768;                // [4096][1536]
  ushort_t* QKV2_bf = KrVr_bf + (size_t)BSROWS * 1536;               // [4096][2304]
  ushort_t* tmp2_bf = tmp1_bf;                                       // reuse (dead)

  dim3 blk(256);

  // 1. prep
  {
    PrepArgs pa;
    pa.j[0] = { dense_w, Wt_dense, 432, 768, 448, 0 };
    pa.j[1] = { rel_kw,  Wt_big,   768, 768, 768, 0 };
    pa.j[2] = { rel_vw,  Wt_big,   768, 768, 768, 768 };
    pa.j[3] = { sat_qw,  Wt_big,   768, 768, 768, 1536 };
    pa.j[4] = { sat_kw,  Wt_big,   768, 768, 768, 2304 };
    pa.j[5] = { sat_vw,  Wt_big,   768, 768, 768, 3072 };
    pa.j[6] = { sat_ow,  Wt_satow, 768, 768, 768, 0 };
    pa.j[7] = { head_w,  Wt_head,  768, 128, 768, 0 };
    pa.bert = bert; pa.bert_bf = bert_bf;
    pa.rkb = rel_kb; pa.rvb = rel_vb; pa.sqb = sat_qb; pa.skb = sat_kb; pa.svb = sat_vb;
    pa.b_merged = b_merged;
    prep_all<<<dim3(24, 24, 9), blk, 0, stream>>>(pa);
  }

  // 2. dense
  gemm_bf16<<<dim3(6, 32), blk, 0, stream>>>(bert_bf, 448, Wt_dense, 448, dense_b,
                                             nullptr, hidden0_bf, HH,
                                             nullptr, 0, 1 << 30, 448);
  // 3. center
  mean_bf<<<dim3(6, 8), blk, 0, stream>>>(hidden0_bf, center);

  // 4. iter-1 QKV
  gemm_bf16<<<dim3(18, 32), blk, 0, stream>>>(hidden0_bf, HH, Wt_big + (size_t)1536 * 768, HH,
                                              b_merged + 1536, nullptr, QKV1_bf, 2304,
                                              nullptr, 0, 1 << 30, HH);
  // 5. center projections (iter1 sat K/V + rel q/k/v)
  {
    SmallJobs jobs;
    jobs.j[0] = { sat_kw, sat_kb, nullptr, Kcen };
    jobs.j[1] = { sat_vw, sat_vb, nullptr, Vcen };
    jobs.j[2] = { rel_qw, rel_qb, nullptr, Qr };
    jobs.j[3] = { rel_kw, rel_kb, nullptr, Krc };
    jobs.j[4] = { rel_vw, rel_vb, nullptr, Vrc };
    gemm_skinny<<<dim3(24, 5), blk, 0, stream>>>(center, jobs);
  }
  // 6. star attention 1
  sat_attn<<<BSROWS, 256, 0, stream>>>(QKV1_bf, QKV1_bf + 768, QKV1_bf + 1536, 2304,
                                       QKV1_bf + 768, QKV1_bf + 1536, 2304,
                                       Kcen, Vcen, ctx_bf);
  // 7. sat output proj + residual
  gemm_bf16<<<dim3(6, 32), blk, 0, stream>>>(ctx_bf, HH, Wt_satow, HH, sat_ob,
                                             hidden0_bf, tmp1_bf, HH,
                                             nullptr, 0, 1 << 30, HH);
  // 8. relu+LN -> csA
  relu_ln_bf<<<BSROWS, 256, 0, stream>>>(tmp1_bf, lns_w, lns_b, csA_bf);

  // 9. merged relKV + iter-2 QKV  (N=3840, split at 1536)
  gemm_bf16<<<dim3(30, 32), blk, 0, stream>>>(csA_bf, HH, Wt_big, HH, b_merged,
                                              nullptr, KrVr_bf, 1536,
                                              QKV2_bf, 2304, 1536, HH);
  // 10. rel attention
  rel_attn<<<dim3(8, 12), 256, 0, stream>>>(Qr, Krc, KrVr_bf, Vrc, KrVr_bf + 768, 1536, ctxr);
  // 11. rel output proj + center residual
  {
    SmallJobs jobs;
    jobs.j[0] = { rel_ow, rel_ob, center, relo };
    gemm_skinny<<<dim3(24, 1), blk, 0, stream>>>(ctxr, jobs);
  }
  // 12. fused relu+LN + iter-2 center projections
  {
    SmallJobs2 jobs;
    jobs.j[0] = { sat_kw, sat_kb, nullptr, Kcen };
    jobs.j[1] = { sat_vw, sat_vb, nullptr, Vcen };
    skinny_ln<<<dim3(24, 2), blk, 0, stream>>>(relo, lnr_w, lnr_b, jobs);
  }
  // 13. star attention 2
  sat_attn<<<BSROWS, 256, 0, stream>>>(QKV2_bf, QKV2_bf + 768, QKV2_bf + 1536, 2304,
                                       QKV1_bf + 768, QKV1_bf + 1536, 2304,
                                       Kcen, Vcen, ctx_bf);
  // 14. sat output proj 2 + residual
  gemm_bf16<<<dim3(6, 32), blk, 0, stream>>>(ctx_bf, HH, Wt_satow, HH, sat_ob,
                                             csA_bf, tmp2_bf, HH,
                                             nullptr, 0, 1 << 30, HH);
  // 15. relu+LN -> csA
  relu_ln_bf<<<BSROWS, 256, 0, stream>>>(tmp2_bf, lns_w, lns_b, csA_bf);

  // 16. fused head GEMM + rope + tail
  head_fused<<<32, blk, 0, stream>>>(csA_bf, Wt_head, head_b, tail_w, tail_b,
                                     qwbuf, kwbuf, bias2);
  // 17. final logits
  final_kernel<<<dim3(16, 16, 8), 256, 0, stream>>>(qwbuf, kwbuf, bias2, amask, out);
}

// Round 6
// 311.769 us; speedup vs baseline: 7.8379x; 1.0826x over previous
//
#include <hip/hip_runtime.h>
#include <cstdint>
#include <cstddef>

#define HH 768
#define SS 512
#define NBATCH 8
#define NLH 12
#define HDIM 64
#define BSROWS 4096
static constexpr float NEGV = -1000000000000.0f;

typedef unsigned short ushort_t;
typedef __attribute__((ext_vector_type(4))) float fx4;
typedef __attribute__((ext_vector_type(8))) short sx8;

__device__ __forceinline__ ushort_t f2bf(float f) {
  uint32_t u = __float_as_uint(f);
  uint32_t r = (u + 0x7FFFu + ((u >> 16) & 1u)) >> 16;
  return (ushort_t)r;
}
__device__ __forceinline__ float bf2f(ushort_t h) {
  return __uint_as_float(((uint32_t)h) << 16);
}
__device__ __forceinline__ float2 ldbf2(const ushort_t* p) {
  uint32_t u = *(const uint32_t*)p;
  return make_float2(__uint_as_float(u << 16), __uint_as_float(u & 0xffff0000u));
}

__device__ __forceinline__ void async_copy16(void* lds, const void* g) {
  __builtin_amdgcn_global_load_lds(
      (const __attribute__((address_space(1))) void*)g,
      (__attribute__((address_space(3))) void*)lds, 16, 0, 0);
}

// ============ bf16 MFMA GEMM: 128x128 tile, BK=64, 4 waves, 1D grid + XCD swizzle.
// dst = (bn >= nsplit) ? Cb2 : Cb.  bias by global col. resb only valid on Cb path.
// colmean != nullptr: atomically accumulate column means per 512-row batch (dense).
__global__ __launch_bounds__(256) void gemm_bf16(
    const ushort_t* __restrict__ A, int lda,
    const ushort_t* __restrict__ B, int ldb,
    const float* __restrict__ bias,
    const ushort_t* __restrict__ resb,
    ushort_t* __restrict__ Cb, int ldo,
    ushort_t* __restrict__ Cb2, int ldo2, int nsplit, int K, int nx,
    float* __restrict__ colmean)
{
  __shared__ ushort_t As[128 * 64];
  __shared__ ushort_t Bs[128 * 64];
  const int tid = threadIdx.x;
  // bijective XCD swizzle (m204): nwg % 8 == 0 guaranteed by caller
  const int nwg = gridDim.x;
  const int q = nwg >> 3;
  const int xcd = blockIdx.x & 7, sidx = blockIdx.x >> 3;
  const int swz = xcd * q + sidx;
  const int bm = (swz / nx) * 128;
  const int bn = (swz % nx) * 128;
  const int l = tid & 63;
  const int w = tid >> 6;
  const int wr = w >> 1, wc = w & 1;
  const int r8 = tid >> 3;
  const int sl = tid & 7;

  fx4 acc[4][4];
#pragma unroll
  for (int m = 0; m < 4; ++m)
#pragma unroll
    for (int n = 0; n < 4; ++n) acc[m][n] = (fx4)0.f;

  for (int k0 = 0; k0 < K; k0 += 64) {
#pragma unroll
    for (int i = 0; i < 4; ++i) {
      int row = i * 32 + r8;
      int srcs = sl ^ (row & 7);
      async_copy16((char*)As + i * 4096 + tid * 16,
                   A + (size_t)(bm + row) * lda + k0 + srcs * 8);
    }
#pragma unroll
    for (int i = 0; i < 4; ++i) {
      int row = i * 32 + r8;
      int srcs = sl ^ (row & 7);
      async_copy16((char*)Bs + i * 4096 + tid * 16,
                   B + (size_t)(bn + row) * ldb + k0 + srcs * 8);
    }
    __syncthreads();
#pragma unroll
    for (int kk = 0; kk < 2; ++kk) {
      sx8 av[4], bv[4];
      const int so = (l >> 4) + kk * 4;
#pragma unroll
      for (int m = 0; m < 4; ++m) {
        int r = wr * 64 + m * 16 + (l & 15);
        av[m] = *(const sx8*)((const char*)As + r * 128 + ((so ^ (r & 7)) * 16));
      }
#pragma unroll
      for (int n = 0; n < 4; ++n) {
        int r = wc * 64 + n * 16 + (l & 15);
        bv[n] = *(const sx8*)((const char*)Bs + r * 128 + ((so ^ (r & 7)) * 16));
      }
#pragma unroll
      for (int m = 0; m < 4; ++m)
#pragma unroll
        for (int n = 0; n < 4; ++n)
          acc[m][n] = __builtin_amdgcn_mfma_f32_16x16x32_bf16(av[m], bv[n], acc[m][n], 0, 0, 0);
    }
    __syncthreads();
  }

  const bool second = (bn >= nsplit);
  ushort_t* dst = second ? Cb2 : Cb;
  const int ld = second ? ldo2 : ldo;
  const int csub = second ? nsplit : 0;
  const int cr0 = bm + wr * 64 + (l >> 4) * 4;
  const int cc0 = bn + wc * 64 + (l & 15);
#pragma unroll
  for (int m = 0; m < 4; ++m) {
#pragma unroll
    for (int n = 0; n < 4; ++n) {
      int col = cc0 + n * 16;
      float bcol = bias[col];
#pragma unroll
      for (int j = 0; j < 4; ++j) {
        int row = cr0 + m * 16 + j;
        size_t off = (size_t)row * ld + (col - csub);
        float v = acc[m][n][j] + bcol;
        if (resb) v += bf2f(resb[off]);
        dst[off] = f2bf(v);
      }
    }
  }

  if (colmean) {
    // per-block column partial sums over 128 rows -> atomic into colmean
    float* scr = (float*)As;   // 8 x 128 floats
    const int cid = wr * 4 + (l >> 4);
#pragma unroll
    for (int n = 0; n < 4; ++n) {
      int colL = wc * 64 + n * 16 + (l & 15);
      float t = 16.0f * bias[bn + colL];
#pragma unroll
      for (int m = 0; m < 4; ++m)
#pragma unroll
        for (int j = 0; j < 4; ++j) t += acc[m][n][j];
      scr[cid * 128 + colL] = t;
    }
    __syncthreads();
    if (tid < 128) {
      float scol = 0.f;
#pragma unroll
      for (int c = 0; c < 8; ++c) scol += scr[c * 128 + tid];
      atomicAdd(&colmean[(bm >> 9) * HH + bn + tid], scol * (1.0f / 512.0f));
    }
  }
}

// ============ fused head GEMM (M-tile 128, N=128) + RoPE + tail-bias epilogue
__global__ __launch_bounds__(256) void head_fused(
    const ushort_t* __restrict__ A,
    const ushort_t* __restrict__ B,
    const float* __restrict__ head_b,
    const float* __restrict__ tail_w,
    const float* __restrict__ tail_b,
    float* __restrict__ qw, float* __restrict__ kw,
    float* __restrict__ bias2)
{
  __shared__ ushort_t As[128 * 64];
  __shared__ ushort_t Bs[128 * 64];
  __shared__ float tile[128][130];
  __shared__ float invt[32];
  const int tid = threadIdx.x;
  const int bm = blockIdx.x * 128;
  const int l = tid & 63;
  const int w = tid >> 6;
  const int wr = w >> 1, wc = w & 1;
  const int r8 = tid >> 3;
  const int sl = tid & 7;

  if (tid < 32) invt[tid] = powf(10000.0f, -(float)tid / 32.0f);

  fx4 acc[4][4];
#pragma unroll
  for (int m = 0; m < 4; ++m)
#pragma unroll
    for (int n = 0; n < 4; ++n) acc[m][n] = (fx4)0.f;

  for (int k0 = 0; k0 < HH; k0 += 64) {
#pragma unroll
    for (int i = 0; i < 4; ++i) {
      int row = i * 32 + r8;
      int srcs = sl ^ (row & 7);
      async_copy16((char*)As + i * 4096 + tid * 16,
                   A + (size_t)(bm + row) * HH + k0 + srcs * 8);
    }
#pragma unroll
    for (int i = 0; i < 4; ++i) {
      int row = i * 32 + r8;
      int srcs = sl ^ (row & 7);
      async_copy16((char*)Bs + i * 4096 + tid * 16,
                   B + (size_t)row * HH + k0 + srcs * 8);
    }
    __syncthreads();
#pragma unroll
    for (int kk = 0; kk < 2; ++kk) {
      sx8 av[4], bv[4];
      const int so = (l >> 4) + kk * 4;
#pragma unroll
      for (int m = 0; m < 4; ++m) {
        int r = wr * 64 + m * 16 + (l & 15);
        av[m] = *(const sx8*)((const char*)As + r * 128 + ((so ^ (r & 7)) * 16));
      }
#pragma unroll
      for (int n = 0; n < 4; ++n) {
        int r = wc * 64 + n * 16 + (l & 15);
        bv[n] = *(const sx8*)((const char*)Bs + r * 128 + ((so ^ (r & 7)) * 16));
      }
#pragma unroll
      for (int m = 0; m < 4; ++m)
#pragma unroll
        for (int n = 0; n < 4; ++n)
          acc[m][n] = __builtin_amdgcn_mfma_f32_16x16x32_bf16(av[m], bv[n], acc[m][n], 0, 0, 0);
    }
    __syncthreads();
  }

  const int cr0 = wr * 64 + (l >> 4) * 4;
  const int cc0 = wc * 64 + (l & 15);
#pragma unroll
  for (int m = 0; m < 4; ++m)
#pragma unroll
    for (int n = 0; n < 4; ++n) {
      int col = cc0 + n * 16;
      float bcol = head_b[col];
#pragma unroll
      for (int j = 0; j < 4; ++j)
        tile[cr0 + m * 16 + j][col] = acc[m][n][j] + bcol;
    }
  __syncthreads();

  for (int t = tid; t < 128 * 32; t += 256) {
    int r = t >> 5, i = t & 31;
    int s = (bm + r) & 511;
    float ang = (float)s * invt[i];
    float sn = sinf(ang), cn = cosf(ang);
    float q0 = tile[r][4 * i + 0], k0 = tile[r][4 * i + 1];
    float q1 = tile[r][4 * i + 2], k1 = tile[r][4 * i + 3];
    float* qp = qw + (size_t)(bm + r) * 64 + i * 2;
    float* kp = kw + (size_t)(bm + r) * 64 + i * 2;
    qp[0] = q0 * cn - q1 * sn; qp[1] = q1 * cn + q0 * sn;
    kp[0] = k0 * cn - k1 * sn; kp[1] = k1 * cn + k0 * sn;
  }
  for (int t = tid; t < 128 * 24; t += 256) {
    int r = t / 24, c = t % 24;
    float acc2 = tail_b[c];
#pragma unroll 16
    for (int k = 0; k < 128; ++k) acc2 = fmaf(tile[r][k], tail_w[k * 24 + c], acc2);
    bias2[(size_t)(bm + r) * 24 + c] = acc2 * 0.5f;
  }
}

// ============ combined prep: z<8 weight transposes; z==8 bert->bf16 + bias concat + center zero
struct TJob { const float* src; ushort_t* dst; int K, N, Kpad, rowOff; };
struct PrepArgs {
  TJob j[8];
  const float* bert; ushort_t* bert_bf;
  const float* rkb; const float* rvb; const float* sqb; const float* skb; const float* svb;
  float* b_merged;
  float* center;     // zeroed each launch (dense accumulates atomically)
};
__global__ __launch_bounds__(256) void prep_all(PrepArgs pa)
{
  if (blockIdx.z < 8) {
    TJob jb = pa.j[blockIdx.z];
    int k0 = blockIdx.x * 32, n0 = blockIdx.y * 32;
    if (k0 >= jb.Kpad || n0 >= jb.N) return;
    __shared__ float t[32][33];
    int tx = threadIdx.x & 31, ty = threadIdx.x >> 5;
#pragma unroll
    for (int i = 0; i < 4; ++i) {
      int k = k0 + ty + i * 8;
      float v = 0.f;
      if (k < jb.K && n0 + tx < jb.N) v = jb.src[(size_t)k * jb.N + n0 + tx];
      t[ty + i * 8][tx] = v;
    }
    __syncthreads();
#pragma unroll
    for (int i = 0; i < 4; ++i) {
      int n = n0 + ty + i * 8;
      int k = k0 + tx;
      if (n < jb.N && k < jb.Kpad)
        jb.dst[(size_t)(jb.rowOff + n) * jb.Kpad + k] = f2bf(t[tx][ty + i * 8]);
    }
  } else {
    const int NB = BSROWS * 448;
    const int total = NB + 3840 + NBATCH * HH;
    int start = (blockIdx.y * 24 + blockIdx.x) * 256 + threadIdx.x;
    for (int i = start; i < total; i += 24 * 24 * 256) {
      if (i < NB) {
        int r = i / 448, c = i % 448;
        pa.bert_bf[i] = (c < 432) ? f2bf(pa.bert[(size_t)r * 432 + c]) : (ushort_t)0;
      } else if (i < NB + 3840) {
        int c = i - NB;
        float v;
        if (c < 768) v = pa.rkb[c];
        else if (c < 1536) v = pa.rvb[c - 768];
        else if (c < 2304) v = pa.sqb[c - 1536];
        else if (c < 3072) v = pa.skb[c - 2304];
        else v = pa.svb[c - 3072];
        pa.b_merged[c] = v;
      } else {
        pa.center[i - NB - 3840] = 0.f;
      }
    }
  }
}

// ============ skinny GEMM: M=8, K=768, N=768 (f32 weights), multi-job
struct SmallJob { const float* W; const float* bias; const float* res; float* C; };
struct SmallJobs { SmallJob j[5]; };
__global__ __launch_bounds__(256) void gemm_skinny(
    const float* __restrict__ A, SmallJobs jobs)
{
  __shared__ float As[8 * HH];
  __shared__ float part[8 * 8 * 32];
  const int tid = threadIdx.x;
  const SmallJob job = jobs.j[blockIdx.y];
#pragma unroll
  for (int i = 0; i < 6; ++i) {
    int idx = tid * 4 + i * 1024;
    *(float4*)&As[idx] = *(const float4*)(A + idx);
  }
  __syncthreads();
  const int c = tid & 31;
  const int col = (blockIdx.x << 5) + c;
  const int ks = tid >> 5;
  const float* Wp = job.W + (size_t)(ks * 96) * HH + col;
  float acc[8] = {};
#pragma unroll 8
  for (int k = 0; k < 96; ++k) {
    float wv = Wp[(size_t)k * HH];
    const float* ap = &As[ks * 96 + k];
#pragma unroll
    for (int m = 0; m < 8; ++m)
      acc[m] = fmaf(ap[m * HH], wv, acc[m]);
  }
#pragma unroll
  for (int m = 0; m < 8; ++m)
    part[ks * 256 + m * 32 + c] = acc[m];
  __syncthreads();
  const int m = tid >> 5;
  const int c2 = tid & 31;
  float s = 0.f;
#pragma unroll
  for (int k = 0; k < 8; ++k) s += part[k * 256 + m * 32 + c2];
  const int outcol = (blockIdx.x << 5) + c2;
  float v = s + job.bias[outcol];
  if (job.res) v += job.res[(size_t)m * HH + outcol];
  job.C[(size_t)m * HH + outcol] = v;
}

// ============ skinny with in-block relu+LN of staged A
struct SmallJobs2 { SmallJob j[2]; };
__global__ __launch_bounds__(256) void skinny_ln(
    const float* __restrict__ relo, const float* __restrict__ lw, const float* __restrict__ lb,
    SmallJobs2 jobs)
{
  __shared__ float As[8 * HH];
  __shared__ float part[8 * 8 * 32];
  const int tid = threadIdx.x;
  const SmallJob job = jobs.j[blockIdx.y];
#pragma unroll
  for (int i = 0; i < 6; ++i) {
    int idx = tid * 4 + i * 1024;
    *(float4*)&As[idx] = *(const float4*)(relo + idx);
  }
  __syncthreads();
  {
    const int row = tid >> 5, lc = tid & 31;
    float s = 0.f, sq = 0.f;
#pragma unroll
    for (int e = 0; e < 24; ++e) {
      float x = fmaxf(As[row * HH + lc * 24 + e], 0.f);
      s += x; sq += x * x;
    }
#pragma unroll
    for (int d = 1; d < 32; d <<= 1) { s += __shfl_xor(s, d); sq += __shfl_xor(sq, d); }
    float mean = s * (1.0f / HH);
    float var = sq * (1.0f / HH) - mean * mean;
    float rstd = rsqrtf(var + 1e-12f);
#pragma unroll
    for (int e = 0; e < 24; ++e) {
      int cc = lc * 24 + e;
      float x = fmaxf(As[row * HH + cc], 0.f);
      As[row * HH + cc] = lw[cc] * (x - mean) * rstd + lb[cc];
    }
  }
  __syncthreads();
  const int c = tid & 31;
  const int col = (blockIdx.x << 5) + c;
  const int ks = tid >> 5;
  const float* Wp = job.W + (size_t)(ks * 96) * HH + col;
  float acc[8] = {};
#pragma unroll 8
  for (int k = 0; k < 96; ++k) {
    float wv = Wp[(size_t)k * HH];
    const float* ap = &As[ks * 96 + k];
#pragma unroll
    for (int m = 0; m < 8; ++m)
      acc[m] = fmaf(ap[m * HH], wv, acc[m]);
  }
#pragma unroll
  for (int m = 0; m < 8; ++m)
    part[ks * 256 + m * 32 + c] = acc[m];
  __syncthreads();
  const int m = tid >> 5;
  const int c2 = tid & 31;
  float s2 = 0.f;
#pragma unroll
  for (int k = 0; k < 8; ++k) s2 += part[k * 256 + m * 32 + c2];
  const int outcol = (blockIdx.x << 5) + c2;
  job.C[(size_t)m * HH + outcol] = s2 + job.bias[outcol];
}

// ============ star attention, ushort2-vectorized: 2 heads/wave, 32-lane reduce
__global__ __launch_bounds__(256) void sat_attn(
    const ushort_t* __restrict__ Qc, const ushort_t* __restrict__ Kc,
    const ushort_t* __restrict__ Vc, int ldq,
    const ushort_t* __restrict__ Kh0, const ushort_t* __restrict__ Vh0, int ldh,
    const float* __restrict__ Kcen, const float* __restrict__ Vcen,
    ushort_t* __restrict__ ctxb)
{
  int i = blockIdx.x;
  int b = i >> 9, s = i & 511;
  int lane = threadIdx.x & 63;
  int wave = threadIdx.x >> 6;
  size_t rb = (size_t)(b * SS + ((s + 1) & 511));
  size_t rs = (size_t)i;
  size_t ra = (size_t)(b * SS + (s == 0 ? (SS - 1) : 0));
  size_t rc = (size_t)b * HH;
  const int half = lane >> 5;
  const int d0 = (lane & 31) * 2;
#pragma unroll
  for (int it = 0; it < 2; ++it) {
    int p = wave + 4 * it;
    if (p >= 6) break;                 // 12 heads = pairs 0..5
    int off = (2 * p + half) * HDIM + d0;
    float2 q  = ldbf2(Qc + rs * ldq + off);
    float2 kb = ldbf2(Kc + rb * ldq + off);
    float2 ks = ldbf2(Kc + rs * ldq + off);
    float2 ka = ldbf2(Kc + ra * ldq + off);
    float2 kh = ldbf2(Kh0 + rs * ldh + off);
    float2 kc = *(const float2*)(Kcen + rc + off);
    float s0 = q.x * kb.x + q.y * kb.y;
    float s1 = q.x * ks.x + q.y * ks.y;
    float s2 = q.x * ka.x + q.y * ka.y;
    float s3 = q.x * kh.x + q.y * kh.y;
    float s4 = q.x * kc.x + q.y * kc.y;
#pragma unroll
    for (int d = 1; d < 32; d <<= 1) {
      s0 += __shfl_xor(s0, d); s1 += __shfl_xor(s1, d); s2 += __shfl_xor(s2, d);
      s3 += __shfl_xor(s3, d); s4 += __shfl_xor(s4, d);
    }
    const float sc = 0.125f;
    s0 *= sc; s1 *= sc; s2 *= sc; s3 *= sc; s4 *= sc;
    float mx = fmaxf(fmaxf(fmaxf(s0, s1), fmaxf(s2, s3)), s4);
    float e0 = __expf(s0 - mx), e1 = __expf(s1 - mx), e2 = __expf(s2 - mx);
    float e3 = __expf(s3 - mx), e4 = __expf(s4 - mx);
    float inv = 1.f / (e0 + e1 + e2 + e3 + e4);
    float2 vb = ldbf2(Vc + rb * ldq + off);
    float2 vs = ldbf2(Vc + rs * ldq + off);
    float2 va = ldbf2(Vc + ra * ldq + off);
    float2 vh = ldbf2(Vh0 + rs * ldh + off);
    float2 vc = *(const float2*)(Vcen + rc + off);
    float vx = e0 * vb.x + e1 * vs.x + e2 * va.x + e3 * vh.x + e4 * vc.x;
    float vy = e0 * vb.y + e1 * vs.y + e2 * va.y + e3 * vh.y + e4 * vc.y;
    uint32_t o = (uint32_t)f2bf(vx * inv) | ((uint32_t)f2bf(vy * inv) << 16);
    *(uint32_t*)(ctxb + rs * HH + off) = o;
  }
}

// ============ relu + layernorm over bf16 rows -> bf16
__global__ __launch_bounds__(256) void relu_ln_bf(
    const ushort_t* __restrict__ x, const float* __restrict__ w, const float* __restrict__ b,
    ushort_t* __restrict__ ybf)
{
  int row = blockIdx.x;
  const ushort_t* xr = x + (size_t)row * HH;
  float v[3];
  float sum = 0.f, sumsq = 0.f;
#pragma unroll
  for (int j = 0; j < 3; ++j) {
    float t = bf2f(xr[threadIdx.x + j * 256]);
    t = fmaxf(t, 0.f);
    v[j] = t;
    sum += t; sumsq += t * t;
  }
#pragma unroll
  for (int d = 1; d < 64; d <<= 1) { sum += __shfl_xor(sum, d); sumsq += __shfl_xor(sumsq, d); }
  __shared__ float ws_[4], wsq_[4];
  int wave = threadIdx.x >> 6, lane = threadIdx.x & 63;
  if (lane == 0) { ws_[wave] = sum; wsq_[wave] = sumsq; }
  __syncthreads();
  sum = ws_[0] + ws_[1] + ws_[2] + ws_[3];
  sumsq = wsq_[0] + wsq_[1] + wsq_[2] + wsq_[3];
  float mean = sum * (1.0f / HH);
  float var = sumsq * (1.0f / HH) - mean * mean;
  float rstd = rsqrtf(var + 1e-12f);
#pragma unroll
  for (int j = 0; j < 3; ++j) {
    int cidx = threadIdx.x + j * 256;
    float o = w[cidx] * (v[j] - mean) * rstd + b[cidx];
    ybf[(size_t)row * HH + cidx] = f2bf(o);
  }
}

// ============ rel attention: Kr/Vr bf16 strided, vectorized K-dot
__global__ __launch_bounds__(256) void rel_attn(
    const float* __restrict__ Qr, const float* __restrict__ Krc, const ushort_t* __restrict__ Kr,
    const float* __restrict__ Vrc, const ushort_t* __restrict__ Vr, int ldkv,
    float* __restrict__ ctx)
{
  int b = blockIdx.x, h = blockIdx.y;
  __shared__ float qs[64];
  __shared__ float sc[513];
  __shared__ float part[4][64];
  __shared__ float redm[4], redsum[4];
  int t = threadIdx.x, lane = t & 63, wave = t >> 6;
  if (t < 64) qs[t] = Qr[b * HH + h * HDIM + t];
  __syncthreads();
  for (int j = t; j < 513; j += 256) {
    float acc = 0.f;
    if (j == 0) {
      const float* kp = Krc + b * HH + h * HDIM;
#pragma unroll
      for (int d = 0; d < HDIM; ++d) acc = fmaf(qs[d], kp[d], acc);
    } else {
      const sx8* kv = (const sx8*)(Kr + (size_t)(b * SS + j - 1) * ldkv + h * HDIM);
#pragma unroll
      for (int dq = 0; dq < 8; ++dq) {
        sx8 v = kv[dq];
#pragma unroll
        for (int e = 0; e < 8; ++e)
          acc = fmaf(qs[dq * 8 + e], bf2f((ushort_t)v[e]), acc);
      }
    }
    sc[j] = acc * 0.125f;
  }
  __syncthreads();
  float m = -1e30f;
  for (int j = t; j < 513; j += 256) m = fmaxf(m, sc[j]);
#pragma unroll
  for (int d = 1; d < 64; d <<= 1) m = fmaxf(m, __shfl_xor(m, d));
  if (lane == 0) redm[wave] = m;
  __syncthreads();
  m = fmaxf(fmaxf(redm[0], redm[1]), fmaxf(redm[2], redm[3]));
  float lsum = 0.f;
  for (int j = t; j < 513; j += 256) { float e = __expf(sc[j] - m); sc[j] = e; lsum += e; }
#pragma unroll
  for (int d = 1; d < 64; d <<= 1) lsum += __shfl_xor(lsum, d);
  if (lane == 0) redsum[wave] = lsum;
  __syncthreads();
  float total = redsum[0] + redsum[1] + redsum[2] + redsum[3];
  float accv = 0.f;
#pragma unroll 8
  for (int j = wave; j < 513; j += 4) {
    float vv = (j == 0) ? Vrc[b * HH + h * HDIM + lane]
                        : bf2f(Vr[(size_t)(b * SS + j - 1) * ldkv + h * HDIM + lane]);
    accv = fmaf(sc[j], vv, accv);
  }
  part[wave][lane] = accv;
  __syncthreads();
  if (wave == 0) {
    float r = (part[0][lane] + part[1][lane] + part[2][lane] + part[3][lane]) / total;
    ctx[b * HH + h * HDIM + lane] = r;
  }
}

// ============ final logits
__global__ __launch_bounds__(256) void final_kernel(
    const float* __restrict__ qw, const float* __restrict__ kw,
    const float* __restrict__ bias2, const float* __restrict__ mask,
    float* __restrict__ out)
{
  int b = blockIdx.z;
  int mt = blockIdx.y * 32;
  int nt = blockIdx.x * 32;
  __shared__ float qs[32][68];
  __shared__ float ks[32][68];
  int t = threadIdx.x;
  {
    int idx = t * 8;
    int r = idx >> 6, c = idx & 63;
    const float* sq = qw + (size_t)(b * SS + mt + r) * 64 + c;
    const float* sk = kw + (size_t)(b * SS + nt + r) * 64 + c;
    *(float4*)&qs[r][c]     = *(const float4*)(sq);
    *(float4*)&qs[r][c + 4] = *(const float4*)(sq + 4);
    *(float4*)&ks[r][c]     = *(const float4*)(sk);
    *(float4*)&ks[r][c + 4] = *(const float4*)(sk + 4);
  }
  __syncthreads();
  int m = t >> 3;
  int n0 = (t & 7) * 4;
  float d0 = 0.f, d1 = 0.f, d2 = 0.f, d3 = 0.f;
#pragma unroll
  for (int d = 0; d < 64; d += 4) {
    float4 qv = *(const float4*)&qs[m][d];
    float4 k0 = *(const float4*)&ks[n0 + 0][d];
    float4 k1 = *(const float4*)&ks[n0 + 1][d];
    float4 k2 = *(const float4*)&ks[n0 + 2][d];
    float4 k3 = *(const float4*)&ks[n0 + 3][d];
    d0 += qv.x * k0.x + qv.y * k0.y + qv.z * k0.z + qv.w * k0.w;
    d1 += qv.x * k1.x + qv.y * k1.y + qv.z * k1.z + qv.w * k1.w;
    d2 += qv.x * k2.x + qv.y * k2.y + qv.z * k2.z + qv.w * k2.w;
    d3 += qv.x * k3.x + qv.y * k3.y + qv.z * k3.z + qv.w * k3.w;
  }
  int gm = mt + m;
  int gn = nt + n0;
  d0 *= 0.125f; d1 *= 0.125f; d2 *= 0.125f; d3 *= 0.125f;
  float mm = mask[b * SS + gm];
  float mn0 = mask[b * SS + gn + 0];
  float mn1 = mask[b * SS + gn + 1];
  float mn2 = mask[b * SS + gn + 2];
  float mn3 = mask[b * SS + gn + 3];
  const float* bmp  = bias2 + (size_t)(b * SS + gm) * 24;
  const float* bnp0 = bias2 + (size_t)(b * SS + gn + 0) * 24;
  const float* bnp1 = bias2 + (size_t)(b * SS + gn + 1) * 24;
  const float* bnp2 = bias2 + (size_t)(b * SS + gn + 2) * 24;
  const float* bnp3 = bias2 + (size_t)(b * SS + gn + 3) * 24;
#pragma unroll
  for (int h = 0; h < NLH; ++h) {
    float tb = bmp[2 * h + 1];
    float v0 = d0 + bnp0[2 * h] + tb;
    float v1 = d1 + bnp1[2 * h] + tb;
    float v2 = d2 + bnp2[2 * h] + tb;
    float v3 = d3 + bnp3[2 * h] + tb;
    v0 = v0 * mm + NEGV * (1.f - mm); v1 = v1 * mm + NEGV * (1.f - mm);
    v2 = v2 * mm + NEGV * (1.f - mm); v3 = v3 * mm + NEGV * (1.f - mm);
    v0 = v0 * mn0 + NEGV * (1.f - mn0); v1 = v1 * mn1 + NEGV * (1.f - mn1);
    v2 = v2 * mn2 + NEGV * (1.f - mn2); v3 = v3 * mn3 + NEGV * (1.f - mn3);
    if (gm > gn + 0) v0 -= 1000000000000.0f;
    if (gm > gn + 1) v1 -= 1000000000000.0f;
    if (gm > gn + 2) v2 -= 1000000000000.0f;
    if (gm > gn + 3) v3 -= 1000000000000.0f;
    float4 o = make_float4(v0, v1, v2, v3);
    *(float4*)(out + ((((size_t)(b * NLH + h)) * SS + gm) * SS + gn)) = o;
  }
}

extern "C" void kernel_launch(void* const* d_in, const int* in_sizes, int n_in,
                              void* d_out, int out_size, void* d_ws, size_t ws_size,
                              hipStream_t stream)
{
  const float* bert    = (const float*)d_in[0];
  const float* amask   = (const float*)d_in[1];
  const float* dense_w = (const float*)d_in[2];
  const float* dense_b = (const float*)d_in[3];
  const float* sat_qw  = (const float*)d_in[4];
  const float* sat_qb  = (const float*)d_in[5];
  const float* sat_kw  = (const float*)d_in[6];
  const float* sat_kb  = (const float*)d_in[7];
  const float* sat_vw  = (const float*)d_in[8];
  const float* sat_vb  = (const float*)d_in[9];
  const float* sat_ow  = (const float*)d_in[10];
  const float* sat_ob  = (const float*)d_in[11];
  const float* rel_qw  = (const float*)d_in[12];
  const float* rel_qb  = (const float*)d_in[13];
  const float* rel_kw  = (const float*)d_in[14];
  const float* rel_kb  = (const float*)d_in[15];
  const float* rel_vw  = (const float*)d_in[16];
  const float* rel_vb  = (const float*)d_in[17];
  const float* rel_ow  = (const float*)d_in[18];
  const float* rel_ob  = (const float*)d_in[19];
  const float* lns_w   = (const float*)d_in[20];
  const float* lns_b   = (const float*)d_in[21];
  const float* lnr_w   = (const float*)d_in[22];
  const float* lnr_b   = (const float*)d_in[23];
  const float* head_w  = (const float*)d_in[24];
  const float* head_b  = (const float*)d_in[25];
  const float* tail_w  = (const float*)d_in[26];
  const float* tail_b  = (const float*)d_in[27];

  float* out = (float*)d_out;
  char*  ws  = (char*)d_ws;

  size_t off = 0;
  auto alloc = [&](size_t bytes) { char* p = ws + off; off += (bytes + 255) & ~(size_t)255; return p; };
  ushort_t* bert_bf   = (ushort_t*)alloc((size_t)BSROWS * 448 * 2);
  ushort_t* Wt_dense  = (ushort_t*)alloc((size_t)768 * 448 * 2);
  ushort_t* Wt_big    = (ushort_t*)alloc((size_t)3840 * 768 * 2);
  ushort_t* Wt_satow  = (ushort_t*)alloc((size_t)768 * 768 * 2);
  ushort_t* Wt_head   = (ushort_t*)alloc((size_t)128 * 768 * 2);
  ushort_t* hidden0_bf= (ushort_t*)alloc((size_t)BSROWS * HH * 2);
  ushort_t* ctx_bf    = (ushort_t*)alloc((size_t)BSROWS * HH * 2);
  ushort_t* csA_bf    = (ushort_t*)alloc((size_t)BSROWS * HH * 2);
  float* b_merged = (float*)alloc(3840 * 4);
  float* center   = (float*)alloc(6144 * 4);
  float* Kcen     = (float*)alloc(6144 * 4);
  float* Vcen     = (float*)alloc(6144 * 4);
  float* Qr       = (float*)alloc(6144 * 4);
  float* Krc      = (float*)alloc(6144 * 4);
  float* Vrc      = (float*)alloc(6144 * 4);
  float* ctxr     = (float*)alloc(6144 * 4);
  float* relo     = (float*)alloc(6144 * 4);
  float* bias2    = (float*)alloc((size_t)BSROWS * 24 * 4);
  float* qwbuf    = (float*)alloc((size_t)BSROWS * 64 * 4);
  float* kwbuf    = (float*)alloc((size_t)BSROWS * 64 * 4);

  ushort_t* QKV1_bf = (ushort_t*)out;
  ushort_t* tmp1_bf = QKV1_bf + (size_t)BSROWS * 2304;
  ushort_t* KrVr_bf = tmp1_bf + (size_t)BSROWS * 768;
  ushort_t* QKV2_bf = KrVr_bf + (size_t)BSROWS * 1536;
  ushort_t* tmp2_bf = tmp1_bf;

  dim3 blk(256);

  // 1. prep (+ zero center each call)
  {
    PrepArgs pa;
    pa.j[0] = { dense_w, Wt_dense, 432, 768, 448, 0 };
    pa.j[1] = { rel_kw,  Wt_big,   768, 768, 768, 0 };
    pa.j[2] = { rel_vw,  Wt_big,   768, 768, 768, 768 };
    pa.j[3] = { sat_qw,  Wt_big,   768, 768, 768, 1536 };
    pa.j[4] = { sat_kw,  Wt_big,   768, 768, 768, 2304 };
    pa.j[5] = { sat_vw,  Wt_big,   768, 768, 768, 3072 };
    pa.j[6] = { sat_ow,  Wt_satow, 768, 768, 768, 0 };
    pa.j[7] = { head_w,  Wt_head,  768, 128, 768, 0 };
    pa.bert = bert; pa.bert_bf = bert_bf;
    pa.rkb = rel_kb; pa.rvb = rel_vb; pa.sqb = sat_qb; pa.skb = sat_kb; pa.svb = sat_vb;
    pa.b_merged = b_merged; pa.center = center;
    prep_all<<<dim3(24, 24, 9), blk, 0, stream>>>(pa);
  }

  // 2. dense + fused column-mean (atomic into zeroed center)
  gemm_bf16<<<dim3(192), blk, 0, stream>>>(bert_bf, 448, Wt_dense, 448, dense_b,
                                           nullptr, hidden0_bf, HH,
                                           nullptr, 0, 1 << 30, 448, 6, center);

  // 3. iter-1 QKV
  gemm_bf16<<<dim3(576), blk, 0, stream>>>(hidden0_bf, HH, Wt_big + (size_t)1536 * 768, HH,
                                           b_merged + 1536, nullptr, QKV1_bf, 2304,
                                           nullptr, 0, 1 << 30, HH, 18, nullptr);
  // 4. center projections
  {
    SmallJobs jobs;
    jobs.j[0] = { sat_kw, sat_kb, nullptr, Kcen };
    jobs.j[1] = { sat_vw, sat_vb, nullptr, Vcen };
    jobs.j[2] = { rel_qw, rel_qb, nullptr, Qr };
    jobs.j[3] = { rel_kw, rel_kb, nullptr, Krc };
    jobs.j[4] = { rel_vw, rel_vb, nullptr, Vrc };
    gemm_skinny<<<dim3(24, 5), blk, 0, stream>>>(center, jobs);
  }
  // 5. star attention 1
  sat_attn<<<BSROWS, 256, 0, stream>>>(QKV1_bf, QKV1_bf + 768, QKV1_bf + 1536, 2304,
                                       QKV1_bf + 768, QKV1_bf + 1536, 2304,
                                       Kcen, Vcen, ctx_bf);
  // 6. sat output proj + residual
  gemm_bf16<<<dim3(192), blk, 0, stream>>>(ctx_bf, HH, Wt_satow, HH, sat_ob,
                                           hidden0_bf, tmp1_bf, HH,
                                           nullptr, 0, 1 << 30, HH, 6, nullptr);
  // 7. relu+LN -> csA
  relu_ln_bf<<<BSROWS, 256, 0, stream>>>(tmp1_bf, lns_w, lns_b, csA_bf);

  // 8. merged relKV + iter-2 QKV (N=3840, split at 1536)
  gemm_bf16<<<dim3(960), blk, 0, stream>>>(csA_bf, HH, Wt_big, HH, b_merged,
                                           nullptr, KrVr_bf, 1536,
                                           QKV2_bf, 2304, 1536, HH, 30, nullptr);
  // 9. rel attention
  rel_attn<<<dim3(8, 12), 256, 0, stream>>>(Qr, Krc, KrVr_bf, Vrc, KrVr_bf + 768, 1536, ctxr);
  // 10. rel output proj + center residual
  {
    SmallJobs jobs;
    jobs.j[0] = { rel_ow, rel_ob, center, relo };
    gemm_skinny<<<dim3(24, 1), blk, 0, stream>>>(ctxr, jobs);
  }
  // 11. fused relu+LN + iter-2 center projections
  {
    SmallJobs2 jobs;
    jobs.j[0] = { sat_kw, sat_kb, nullptr, Kcen };
    jobs.j[1] = { sat_vw, sat_vb, nullptr, Vcen };
    skinny_ln<<<dim3(24, 2), blk, 0, stream>>>(relo, lnr_w, lnr_b, jobs);
  }
  // 12. star attention 2
  sat_attn<<<BSROWS, 256, 0, stream>>>(QKV2_bf, QKV2_bf + 768, QKV2_bf + 1536, 2304,
                                       QKV1_bf + 768, QKV1_bf + 1536, 2304,
                                       Kcen, Vcen, ctx_bf);
  // 13. sat output proj 2 + residual
  gemm_bf16<<<dim3(192), blk, 0, stream>>>(ctx_bf, HH, Wt_satow, HH, sat_ob,
                                           csA_bf, tmp2_bf, HH,
                                           nullptr, 0, 1 << 30, HH, 6, nullptr);
  // 14. relu+LN -> csA
  relu_ln_bf<<<BSROWS, 256, 0, stream>>>(tmp2_bf, lns_w, lns_b, csA_bf);

  // 15. fused head GEMM + rope + tail
  head_fused<<<32, blk, 0, stream>>>(csA_bf, Wt_head, head_b, tail_w, tail_b,
                                     qwbuf, kwbuf, bias2);
  // 16. final logits
  final_kernel<<<dim3(16, 16, 8), 256, 0, stream>>>(qwbuf, kwbuf, bias2, amask, out);
}